// Round 1
// baseline (4462.489 us; speedup 1.0000x reference)
//
#include <hip/hip_runtime.h>

#define NN 50000
#define EE 800000
#define EPN 850000   // EE + NN (self loops appended)

// ---------- helpers ----------
__device__ __forceinline__ unsigned fmap(float f) {
  int s = __float_as_int(f);
  return (s >= 0) ? ((unsigned)s | 0x80000000u) : ~((unsigned)s);
}
__device__ __forceinline__ float funmap(unsigned u) {
  int s = (u & 0x80000000u) ? (int)(u & 0x7FFFFFFFu) : (int)(~u);
  return __int_as_float(s);
}
__device__ __forceinline__ float eluf(float v) { return v > 0.f ? v : expm1f(v); }

// ---------- generic f32 GEMM: C[M,N] = A[M,K] @ B[K,N]; N%64==0, K%16==0 ----------
__global__ __launch_bounds__(256) void gemm_f32(const float* __restrict__ A,
                                                const float* __restrict__ B,
                                                float* __restrict__ C,
                                                int M, int N, int K) {
  __shared__ float As[16][65];
  __shared__ float Bs[16][64];
  int tid = threadIdx.x;
  int row0 = blockIdx.y * 64, col0 = blockIdx.x * 64;
  int tx = tid & 15, ty = tid >> 4;
  float acc[4][4] = {};
  for (int k0 = 0; k0 < K; k0 += 16) {
    {
      int r = tid >> 2;
      int kk = (tid & 3) * 4;
      float4 av = make_float4(0.f, 0.f, 0.f, 0.f);
      if (row0 + r < M) av = *(const float4*)&A[(size_t)(row0 + r) * K + k0 + kk];
      As[kk + 0][r] = av.x; As[kk + 1][r] = av.y; As[kk + 2][r] = av.z; As[kk + 3][r] = av.w;
    }
    {
      int kk = tid >> 4;
      int c = (tid & 15) * 4;
      *(float4*)&Bs[kk][c] = *(const float4*)&B[(size_t)(k0 + kk) * N + col0 + c];
    }
    __syncthreads();
#pragma unroll
    for (int k = 0; k < 16; ++k) {
      float a[4], b[4];
#pragma unroll
      for (int i = 0; i < 4; ++i) a[i] = As[k][ty * 4 + i];
#pragma unroll
      for (int j = 0; j < 4; ++j) b[j] = Bs[k][tx * 4 + j];
#pragma unroll
      for (int i = 0; i < 4; ++i)
#pragma unroll
        for (int j = 0; j < 4; ++j) acc[i][j] += a[i] * b[j];
    }
    __syncthreads();
  }
#pragma unroll
  for (int i = 0; i < 4; ++i) {
    int r = row0 + ty * 4 + i;
    if (r < M)
      *(float4*)&C[(size_t)r * N + col0 + tx * 4] =
          make_float4(acc[i][0], acc[i][1], acc[i][2], acc[i][3]);
  }
}

// ---------- edge logits, D=256 (H=2, C=128): wave per edge ----------
__global__ __launch_bounds__(256) void edge_logits_256(const float* __restrict__ xt,
                                                       const int* __restrict__ ei,
                                                       float* __restrict__ logit,
                                                       unsigned* __restrict__ mmax) {
  int wv = (int)((blockIdx.x * (size_t)blockDim.x + threadIdx.x) >> 6);
  int lane = threadIdx.x & 63;
  if (wv >= EPN) return;
  int s, d;
  if (wv < EE) { s = ei[wv]; d = ei[EE + wv]; } else { s = d = wv - EE; }
  float4 a = ((const float4*)(xt + (size_t)s * 256))[lane];
  float4 b = ((const float4*)(xt + (size_t)d * 256))[lane];
  float p = a.x * b.x + a.y * b.y + a.z * b.z + a.w * b.w;
#pragma unroll
  for (int o = 1; o < 32; o <<= 1) p += __shfl_xor(p, o);  // reduce within 32-lane halves
  p *= 0.08838834764831843f;  // 1/sqrt(128)
  if (lane == 0 || lane == 32) {
    int h = lane >> 5;
    logit[(size_t)wv * 2 + h] = p;
    atomicMax(&mmax[(size_t)d * 2 + h], fmap(p));
  }
}

// ---------- edge logits, D=64 (H=2, C=32): wave per edge ----------
__global__ __launch_bounds__(256) void edge_logits_64(const float* __restrict__ xt,
                                                      const int* __restrict__ ei,
                                                      float* __restrict__ logit,
                                                      unsigned* __restrict__ mmax,
                                                      float scale) {
  int wv = (int)((blockIdx.x * (size_t)blockDim.x + threadIdx.x) >> 6);
  int lane = threadIdx.x & 63;
  if (wv >= EPN) return;
  int s, d;
  if (wv < EE) { s = ei[wv]; d = ei[EE + wv]; } else { s = d = wv - EE; }
  float p = xt[(size_t)s * 64 + lane] * xt[(size_t)d * 64 + lane];
#pragma unroll
  for (int o = 1; o < 32; o <<= 1) p += __shfl_xor(p, o);
  p *= scale;
  if (lane == 0 || lane == 32) {
    int h = lane >> 5;
    logit[(size_t)wv * 2 + h] = p;
    atomicMax(&mmax[(size_t)d * 2 + h], fmap(p));
  }
}

// ---------- exp(e - m) and segment-sum ----------
__global__ __launch_bounds__(256) void softmax_denom(float* __restrict__ logit_ex,
                                                     const unsigned* __restrict__ mmax,
                                                     float* __restrict__ ssum,
                                                     const int* __restrict__ ei) {
  size_t i = blockIdx.x * (size_t)blockDim.x + threadIdx.x;
  if (i >= (size_t)EPN * 2) return;
  int e = (int)(i >> 1), h = (int)(i & 1);
  int d = (e < EE) ? ei[EE + e] : e - EE;
  float mm = funmap(mmax[(size_t)d * 2 + h]);
  float ex = expf(logit_ex[i] - mm);
  logit_ex[i] = ex;
  atomicAdd(&ssum[(size_t)d * 2 + h], ex);
}

// ---------- aggregation D=256 ----------
__global__ __launch_bounds__(256) void aggregate_256(const float* __restrict__ xt,
                                                     const float* __restrict__ exb,
                                                     const float* __restrict__ ssum,
                                                     const int* __restrict__ ei,
                                                     float* __restrict__ outb) {
  int wv = (int)((blockIdx.x * (size_t)blockDim.x + threadIdx.x) >> 6);
  int lane = threadIdx.x & 63;
  if (wv >= EPN) return;
  int s, d;
  if (wv < EE) { s = ei[wv]; d = ei[EE + wv]; } else { s = d = wv - EE; }
  int h = lane >> 5;
  float al = exb[(size_t)wv * 2 + h] / (ssum[(size_t)d * 2 + h] + 1e-16f);
  float4 a = ((const float4*)(xt + (size_t)s * 256))[lane];
  float* o = outb + (size_t)d * 256 + lane * 4;
  atomicAdd(o + 0, al * a.x);
  atomicAdd(o + 1, al * a.y);
  atomicAdd(o + 2, al * a.z);
  atomicAdd(o + 3, al * a.w);
}

// ---------- aggregation D=64 (optionally writes alpha) ----------
__global__ __launch_bounds__(256) void aggregate_64(const float* __restrict__ xt,
                                                    const float* __restrict__ exb,
                                                    const float* __restrict__ ssum,
                                                    const int* __restrict__ ei,
                                                    float* __restrict__ outb,
                                                    float* __restrict__ alpha_out) {
  int wv = (int)((blockIdx.x * (size_t)blockDim.x + threadIdx.x) >> 6);
  int lane = threadIdx.x & 63;
  if (wv >= EPN) return;
  int s, d;
  if (wv < EE) { s = ei[wv]; d = ei[EE + wv]; } else { s = d = wv - EE; }
  int h = lane >> 5;
  float al = exb[(size_t)wv * 2 + h] / (ssum[(size_t)d * 2 + h] + 1e-16f);
  float a = xt[(size_t)s * 64 + lane];
  atomicAdd(&outb[(size_t)d * 64 + lane], al * a);
  if (alpha_out && (lane == 0 || lane == 32)) alpha_out[(size_t)wv * 2 + h] = al;
}

// ---------- aux class head: h = (elu(xt@Wh1+bh1))@Wh2+bh2, per head ----------
template <int C>
__global__ __launch_bounds__(128) void aux_head(const float* __restrict__ xt,   // [N, 2*C]
                                                const float* __restrict__ Wh1,  // [C,64]
                                                const float* __restrict__ bh1,  // [64]
                                                const float* __restrict__ Wh2,  // [64,32]
                                                const float* __restrict__ bh2,  // [32]
                                                float* __restrict__ hout,       // [N,64]
                                                float scale) {
  __shared__ float w1s[C * 64];
  __shared__ float w2s[64 * 32];
  __shared__ float b1s[64], b2s[32];
  __shared__ float xrow[2 * C];
  __shared__ float hid[128];
  int tid = threadIdx.x;
  for (int i = tid; i < C * 64; i += 128) w1s[i] = Wh1[i];
  for (int i = tid; i < 64 * 32; i += 128) w2s[i] = Wh2[i];
  if (tid < 64) b1s[tid] = bh1[tid];
  if (tid < 32) b2s[tid] = bh2[tid];
  __syncthreads();
  for (int n = blockIdx.x; n < NN; n += gridDim.x) {
    for (int i = tid; i < 2 * C; i += 128) xrow[i] = xt[(size_t)n * 2 * C + i];
    __syncthreads();
    int h = tid >> 6, j = tid & 63;
    float acc = b1s[j];
#pragma unroll 8
    for (int c = 0; c < C; ++c) acc += xrow[h * C + c] * w1s[c * 64 + j];
    hid[tid] = eluf(acc);
    __syncthreads();
    if (tid < 64) {
      int hh = tid >> 5, k = tid & 31;
      float o = b2s[k];
#pragma unroll
      for (int jj = 0; jj < 64; ++jj) o += hid[hh * 64 + jj] * w2s[jj * 32 + k];
      hout[(size_t)n * 64 + tid] = o * scale;
    }
    __syncthreads();
  }
}

// ---------- LayerNorm(+ELU) D=256, in place: wave per node ----------
__global__ __launch_bounds__(256) void ln_elu_256(float* __restrict__ x,
                                                  const float* __restrict__ g,
                                                  const float* __restrict__ b) {
  int node = (int)((blockIdx.x * (size_t)blockDim.x + threadIdx.x) >> 6);
  int lane = threadIdx.x & 63;
  if (node >= NN) return;
  float4* row = (float4*)(x + (size_t)node * 256);
  float4 v = row[lane];
  float s = v.x + v.y + v.z + v.w;
#pragma unroll
  for (int o = 1; o < 64; o <<= 1) s += __shfl_xor(s, o);
  float mean = s * (1.f / 256.f);
  float dx = v.x - mean, dy = v.y - mean, dz = v.z - mean, dw = v.w - mean;
  float q = dx * dx + dy * dy + dz * dz + dw * dw;
#pragma unroll
  for (int o = 1; o < 64; o <<= 1) q += __shfl_xor(q, o);
  float rstd = rsqrtf(q * (1.f / 256.f) + 1e-5f);
  float4 gg = ((const float4*)g)[lane], bb = ((const float4*)b)[lane];
  float4 r;
  r.x = eluf(dx * rstd * gg.x + bb.x);
  r.y = eluf(dy * rstd * gg.y + bb.y);
  r.z = eluf(dz * rstd * gg.z + bb.z);
  r.w = eluf(dw * rstd * gg.w + bb.w);
  row[lane] = r;
}

// ---------- LayerNorm(+ELU) D=64, in place: wave per node ----------
__global__ __launch_bounds__(256) void ln_elu_64(float* __restrict__ x,
                                                 const float* __restrict__ g,
                                                 const float* __restrict__ b) {
  int node = (int)((blockIdx.x * (size_t)blockDim.x + threadIdx.x) >> 6);
  int lane = threadIdx.x & 63;
  if (node >= NN) return;
  float v = x[(size_t)node * 64 + lane];
  float s = v;
#pragma unroll
  for (int o = 1; o < 64; o <<= 1) s += __shfl_xor(s, o);
  float mean = s * (1.f / 64.f);
  float dv = v - mean;
  float q = dv * dv;
#pragma unroll
  for (int o = 1; o < 64; o <<= 1) q += __shfl_xor(q, o);
  float rstd = rsqrtf(q * (1.f / 64.f) + 1e-5f);
  x[(size_t)node * 64 + lane] = eluf(dv * rstd * g[lane] + b[lane]);
}

// ---------- layer3 epilogue: mean over heads then LN over 32 dims ----------
__global__ __launch_bounds__(256) void ln3_kernel(const float* __restrict__ agg,  // [N,64]
                                                  const float* __restrict__ g,
                                                  const float* __restrict__ b,
                                                  float* __restrict__ out) {  // [N,32]
  int wv = (int)((blockIdx.x * (size_t)blockDim.x + threadIdx.x) >> 6);
  int lane = threadIdx.x & 63;
  int node = wv * 2 + (lane >> 5);
  int c = lane & 31;
  if (node >= NN) return;
  float y = 0.5f * (agg[(size_t)node * 64 + c] + agg[(size_t)node * 64 + 32 + c]);
  float s = y;
#pragma unroll
  for (int o = 1; o < 32; o <<= 1) s += __shfl_xor(s, o);
  float mean = s * (1.f / 32.f);
  float dy = y - mean;
  float q = dy * dy;
#pragma unroll
  for (int o = 1; o < 32; o <<= 1) q += __shfl_xor(q, o);
  float rstd = rsqrtf(q * (1.f / 32.f) + 1e-5f);
  out[(size_t)node * 32 + c] = dy * rstd * g[c] + b[c];
}

extern "C" void kernel_launch(void* const* d_in, const int* in_sizes, int n_in,
                              void* d_out, int out_size, void* d_ws, size_t ws_size,
                              hipStream_t stream) {
  const float* x    = (const float*)d_in[0];
  const int*   ei   = (const int*)d_in[1];
  const float* W1   = (const float*)d_in[2];
  const float* Wh1a = (const float*)d_in[3];
  const float* bh1a = (const float*)d_in[4];
  const float* Wh2a = (const float*)d_in[5];
  const float* bh2a = (const float*)d_in[6];
  const float* g1   = (const float*)d_in[7];
  const float* b1   = (const float*)d_in[8];
  const float* W2   = (const float*)d_in[9];
  const float* Wh1b = (const float*)d_in[10];
  const float* bh1b = (const float*)d_in[11];
  const float* Wh2b = (const float*)d_in[12];
  const float* bh2b = (const float*)d_in[13];
  const float* g2   = (const float*)d_in[14];
  const float* b2   = (const float*)d_in[15];
  const float* W3   = (const float*)d_in[16];
  const float* Wh1c = (const float*)d_in[17];
  const float* bh1c = (const float*)d_in[18];
  const float* Wh2c = (const float*)d_in[19];
  const float* bh2c = (const float*)d_in[20];
  const float* g3   = (const float*)d_in[21];
  const float* b3   = (const float*)d_in[22];

  float* out  = (float*)d_out;
  float* o_x3 = out;                           // N*32
  float* o_h1 = out + (size_t)NN * 32;         // N*64
  float* o_h2 = o_h1 + (size_t)NN * 64;        // N*64
  float* o_h3 = o_h2 + (size_t)NN * 64;        // N*64
  float* o_al = o_h3 + (size_t)NN * 64;        // EPN*2

  float* ws  = (float*)d_ws;
  float* A   = ws;                             // N*256 (xt buffer)
  float* Bb  = ws + (size_t)NN * 256;          // N*256 (agg / x buffer)
  float* exb = Bb + (size_t)NN * 256;          // EPN*2
  unsigned* mM = (unsigned*)(exb + (size_t)EPN * 2);  // N*2
  float* sS = (float*)mM + (size_t)NN * 2;     // N*2

  dim3 blk(256);
  int gEdgeW = (EPN + 3) / 4;
  int gPairs = (int)(((size_t)EPN * 2 + 255) / 256);
  int gNodeW = (NN * 64) / 256;
  int gLn3 = ((NN / 2) * 64) / 256;
  int gRows = (NN + 63) / 64;

  // ---------------- Layer 1: 512 -> 2x128 (concat) ----------------
  gemm_f32<<<dim3(4, gRows), blk, 0, stream>>>(x, W1, A, NN, 256, 512);
  hipMemsetAsync(mM, 0, (size_t)NN * 2 * 4, stream);
  hipMemsetAsync(sS, 0, (size_t)NN * 2 * 4, stream);
  hipMemsetAsync(Bb, 0, (size_t)NN * 256 * 4, stream);
  aux_head<128><<<2048, 128, 0, stream>>>(A, Wh1a, bh1a, Wh2a, bh2a, o_h1, 1.0f);
  edge_logits_256<<<gEdgeW, blk, 0, stream>>>(A, ei, exb, mM);
  softmax_denom<<<gPairs, blk, 0, stream>>>(exb, mM, sS, ei);
  aggregate_256<<<gEdgeW, blk, 0, stream>>>(A, exb, sS, ei, Bb);
  ln_elu_256<<<gNodeW, blk, 0, stream>>>(Bb, g1, b1);

  // ---------------- Layer 2: 256 -> 2x32 (concat) ----------------
  gemm_f32<<<dim3(1, gRows), blk, 0, stream>>>(Bb, W2, A, NN, 64, 256);
  hipMemsetAsync(mM, 0, (size_t)NN * 2 * 4, stream);
  hipMemsetAsync(sS, 0, (size_t)NN * 2 * 4, stream);
  hipMemsetAsync(Bb, 0, (size_t)NN * 64 * 4, stream);
  aux_head<32><<<2048, 128, 0, stream>>>(A, Wh1b, bh1b, Wh2b, bh2b, o_h2, 0.5f);
  edge_logits_64<<<gEdgeW, blk, 0, stream>>>(A, ei, exb, mM, 0.17677669529663687f);
  softmax_denom<<<gPairs, blk, 0, stream>>>(exb, mM, sS, ei);
  aggregate_64<<<gEdgeW, blk, 0, stream>>>(A, exb, sS, ei, Bb, nullptr);
  ln_elu_64<<<gNodeW, blk, 0, stream>>>(Bb, g2, b2);

  // ---------------- Layer 3: 64 -> 2x32 (mean) ----------------
  gemm_f32<<<dim3(1, gRows), blk, 0, stream>>>(Bb, W3, A, NN, 64, 64);
  hipMemsetAsync(mM, 0, (size_t)NN * 2 * 4, stream);
  hipMemsetAsync(sS, 0, (size_t)NN * 2 * 4, stream);
  hipMemsetAsync(Bb, 0, (size_t)NN * 64 * 4, stream);
  aux_head<32><<<2048, 128, 0, stream>>>(A, Wh1c, bh1c, Wh2c, bh2c, o_h3, 1.0f);
  edge_logits_64<<<gEdgeW, blk, 0, stream>>>(A, ei, exb, mM, 0.17677669529663687f);
  softmax_denom<<<gPairs, blk, 0, stream>>>(exb, mM, sS, ei);
  aggregate_64<<<gEdgeW, blk, 0, stream>>>(A, exb, sS, ei, Bb, o_al);
  ln3_kernel<<<gLn3, blk, 0, stream>>>(Bb, g3, b3, o_x3);
}

// Round 2
// 1599.538 us; speedup vs baseline: 2.7899x; 2.7899x over previous
//
#include <hip/hip_runtime.h>

#define NN 50000
#define EE 800000
#define EPN 850000   // EE + NN (self loops appended)

// ---------- helpers ----------
__device__ __forceinline__ float eluf(float v) { return v > 0.f ? v : expm1f(v); }

// ---------- generic f32 GEMM: C[M,N] = A[M,K] @ B[K,N]; N%64==0, K%16==0 ----------
__global__ __launch_bounds__(256) void gemm_f32(const float* __restrict__ A,
                                                const float* __restrict__ B,
                                                float* __restrict__ C,
                                                int M, int N, int K) {
  __shared__ float As[16][65];
  __shared__ float Bs[16][64];
  int tid = threadIdx.x;
  int row0 = blockIdx.y * 64, col0 = blockIdx.x * 64;
  int tx = tid & 15, ty = tid >> 4;
  float acc[4][4] = {};
  for (int k0 = 0; k0 < K; k0 += 16) {
    {
      int r = tid >> 2;
      int kk = (tid & 3) * 4;
      float4 av = make_float4(0.f, 0.f, 0.f, 0.f);
      if (row0 + r < M) av = *(const float4*)&A[(size_t)(row0 + r) * K + k0 + kk];
      As[kk + 0][r] = av.x; As[kk + 1][r] = av.y; As[kk + 2][r] = av.z; As[kk + 3][r] = av.w;
    }
    {
      int kk = tid >> 4;
      int c = (tid & 15) * 4;
      *(float4*)&Bs[kk][c] = *(const float4*)&B[(size_t)(k0 + kk) * N + col0 + c];
    }
    __syncthreads();
#pragma unroll
    for (int k = 0; k < 16; ++k) {
      float a[4], b[4];
#pragma unroll
      for (int i = 0; i < 4; ++i) a[i] = As[k][ty * 4 + i];
#pragma unroll
      for (int j = 0; j < 4; ++j) b[j] = Bs[k][tx * 4 + j];
#pragma unroll
      for (int i = 0; i < 4; ++i)
#pragma unroll
        for (int j = 0; j < 4; ++j) acc[i][j] += a[i] * b[j];
    }
    __syncthreads();
  }
#pragma unroll
  for (int i = 0; i < 4; ++i) {
    int r = row0 + ty * 4 + i;
    if (r < M)
      *(float4*)&C[(size_t)r * N + col0 + tx * 4] =
          make_float4(acc[i][0], acc[i][1], acc[i][2], acc[i][3]);
  }
}

// ---------- CSR build ----------
__global__ __launch_bounds__(256) void hist_kernel(const int* __restrict__ ei,
                                                   int* __restrict__ cnt) {
  int e = blockIdx.x * 256 + threadIdx.x;
  if (e >= EPN) return;
  int d = (e < EE) ? ei[EE + e] : e - EE;
  atomicAdd(&cnt[d], 1);
}

__global__ __launch_bounds__(1024) void scan_kernel(const int* __restrict__ cnt,
                                                    int* __restrict__ rowptr,
                                                    int* __restrict__ fill) {
  __shared__ int lds[1024];
  __shared__ int carry_s;
  int t = threadIdx.x;
  if (t == 0) { carry_s = 0; rowptr[0] = 0; }
  __syncthreads();
  for (int base = 0; base < NN; base += 1024) {
    int idx = base + t;
    int v = (idx < NN) ? cnt[idx] : 0;
    lds[t] = v;
    __syncthreads();
    for (int off = 1; off < 1024; off <<= 1) {
      int add = (t >= off) ? lds[t - off] : 0;
      __syncthreads();
      lds[t] += add;
      __syncthreads();
    }
    int inc = lds[t] + carry_s;
    if (idx < NN) { rowptr[idx + 1] = inc; fill[idx] = inc - v; }
    __syncthreads();
    if (t == 1023) carry_s = inc;
    __syncthreads();
  }
}

__global__ __launch_bounds__(256) void scatter_kernel(const int* __restrict__ ei,
                                                      int* __restrict__ fill,
                                                      int* __restrict__ eids) {
  int e = blockIdx.x * 256 + threadIdx.x;
  if (e >= EPN) return;
  int d = (e < EE) ? ei[EE + e] : e - EE;
  int pos = atomicAdd(&fill[d], 1);
  eids[pos] = e;
}

// ---------- fused per-node GAT edge phase, D=256 (H=2, C=128) ----------
// wave per node: logits (dst row in regs) -> max -> denom -> weighted gather-sum
__global__ __launch_bounds__(256) void gat_node_256(const float* __restrict__ xt,
                                                    const int* __restrict__ ei,
                                                    const int* __restrict__ rowptr,
                                                    const int* __restrict__ eids,
                                                    float* __restrict__ logit,
                                                    float* __restrict__ outb) {
  int node = (int)((blockIdx.x * (size_t)blockDim.x + threadIdx.x) >> 6);
  int lane = threadIdx.x & 63;
  if (node >= NN) return;
  int half = lane >> 5;
  int l32 = lane & 31;
  int start = rowptr[node], end = rowptr[node + 1];
  float4 dstv = ((const float4*)(xt + (size_t)node * 256))[lane];
  // pass A: logits + running max
  float m = -1e30f;
  for (int i = start; i < end; ++i) {
    int e = eids[i];
    int src = (e < EE) ? ei[e] : e - EE;
    float4 a = ((const float4*)(xt + (size_t)src * 256))[lane];
    float p = a.x * dstv.x + a.y * dstv.y + a.z * dstv.z + a.w * dstv.w;
#pragma unroll
    for (int o = 1; o < 32; o <<= 1) p += __shfl_xor(p, o);
    p *= 0.08838834764831843f;  // 1/sqrt(128)
    if (l32 == 0) logit[(size_t)e * 2 + half] = p;
    m = fmaxf(m, p);
  }
  // pass B: denom
  float s = 0.f;
  for (int i = start + l32; i < end; i += 32) {
    int e = eids[i];
    s += expf(logit[(size_t)e * 2 + half] - m);
  }
#pragma unroll
  for (int o = 1; o < 32; o <<= 1) s += __shfl_xor(s, o);
  float inv = 1.f / (s + 1e-16f);
  // pass C: weighted accumulate
  float4 acc = make_float4(0.f, 0.f, 0.f, 0.f);
  for (int i = start; i < end; ++i) {
    int e = eids[i];
    int src = (e < EE) ? ei[e] : e - EE;
    float al = expf(logit[(size_t)e * 2 + half] - m) * inv;
    float4 a = ((const float4*)(xt + (size_t)src * 256))[lane];
    acc.x += al * a.x; acc.y += al * a.y; acc.z += al * a.z; acc.w += al * a.w;
  }
  ((float4*)(outb + (size_t)node * 256))[lane] = acc;
}

// ---------- fused per-node GAT edge phase, D=64 (H=2, C=32) ----------
__global__ __launch_bounds__(256) void gat_node_64(const float* __restrict__ xt,
                                                   const int* __restrict__ ei,
                                                   const int* __restrict__ rowptr,
                                                   const int* __restrict__ eids,
                                                   float* __restrict__ logit,
                                                   float* __restrict__ outb,
                                                   float* __restrict__ alpha_out) {
  int node = (int)((blockIdx.x * (size_t)blockDim.x + threadIdx.x) >> 6);
  int lane = threadIdx.x & 63;
  if (node >= NN) return;
  int half = lane >> 5;
  int l32 = lane & 31;
  int start = rowptr[node], end = rowptr[node + 1];
  float dv = xt[(size_t)node * 64 + lane];
  float m = -1e30f;
  for (int i = start; i < end; ++i) {
    int e = eids[i];
    int src = (e < EE) ? ei[e] : e - EE;
    float p = xt[(size_t)src * 64 + lane] * dv;
#pragma unroll
    for (int o = 1; o < 32; o <<= 1) p += __shfl_xor(p, o);
    p *= 0.17677669529663687f;  // 1/sqrt(32)
    if (l32 == 0) logit[(size_t)e * 2 + half] = p;
    m = fmaxf(m, p);
  }
  float s = 0.f;
  for (int i = start + l32; i < end; i += 32) {
    int e = eids[i];
    s += expf(logit[(size_t)e * 2 + half] - m);
  }
#pragma unroll
  for (int o = 1; o < 32; o <<= 1) s += __shfl_xor(s, o);
  float inv = 1.f / (s + 1e-16f);
  float acc = 0.f;
  for (int i = start; i < end; ++i) {
    int e = eids[i];
    int src = (e < EE) ? ei[e] : e - EE;
    float al = expf(logit[(size_t)e * 2 + half] - m) * inv;
    acc += al * xt[(size_t)src * 64 + lane];
    if (alpha_out && l32 == 0) alpha_out[(size_t)e * 2 + half] = al;
  }
  outb[(size_t)node * 64 + lane] = acc;
}

// ---------- aux class head: h = (elu(xt@Wh1+bh1))@Wh2+bh2, per head ----------
template <int C>
__global__ __launch_bounds__(128) void aux_head(const float* __restrict__ xt,   // [N, 2*C]
                                                const float* __restrict__ Wh1,  // [C,64]
                                                const float* __restrict__ bh1,  // [64]
                                                const float* __restrict__ Wh2,  // [64,32]
                                                const float* __restrict__ bh2,  // [32]
                                                float* __restrict__ hout,       // [N,64]
                                                float scale) {
  __shared__ float w1s[C * 64];
  __shared__ float w2s[64 * 32];
  __shared__ float b1s[64], b2s[32];
  __shared__ float xrow[2 * C];
  __shared__ float hid[128];
  int tid = threadIdx.x;
  for (int i = tid; i < C * 64; i += 128) w1s[i] = Wh1[i];
  for (int i = tid; i < 64 * 32; i += 128) w2s[i] = Wh2[i];
  if (tid < 64) b1s[tid] = bh1[tid];
  if (tid < 32) b2s[tid] = bh2[tid];
  __syncthreads();
  for (int n = blockIdx.x; n < NN; n += gridDim.x) {
    for (int i = tid; i < 2 * C; i += 128) xrow[i] = xt[(size_t)n * 2 * C + i];
    __syncthreads();
    int h = tid >> 6, j = tid & 63;
    float acc = b1s[j];
#pragma unroll 8
    for (int c = 0; c < C; ++c) acc += xrow[h * C + c] * w1s[c * 64 + j];
    hid[tid] = eluf(acc);
    __syncthreads();
    if (tid < 64) {
      int hh = tid >> 5, k = tid & 31;
      float o = b2s[k];
#pragma unroll
      for (int jj = 0; jj < 64; ++jj) o += hid[hh * 64 + jj] * w2s[jj * 32 + k];
      hout[(size_t)n * 64 + tid] = o * scale;
    }
    __syncthreads();
  }
}

// ---------- LayerNorm(+ELU) D=256, in place: wave per node ----------
__global__ __launch_bounds__(256) void ln_elu_256(float* __restrict__ x,
                                                  const float* __restrict__ g,
                                                  const float* __restrict__ b) {
  int node = (int)((blockIdx.x * (size_t)blockDim.x + threadIdx.x) >> 6);
  int lane = threadIdx.x & 63;
  if (node >= NN) return;
  float4* row = (float4*)(x + (size_t)node * 256);
  float4 v = row[lane];
  float s = v.x + v.y + v.z + v.w;
#pragma unroll
  for (int o = 1; o < 64; o <<= 1) s += __shfl_xor(s, o);
  float mean = s * (1.f / 256.f);
  float dx = v.x - mean, dy = v.y - mean, dz = v.z - mean, dw = v.w - mean;
  float q = dx * dx + dy * dy + dz * dz + dw * dw;
#pragma unroll
  for (int o = 1; o < 64; o <<= 1) q += __shfl_xor(q, o);
  float rstd = rsqrtf(q * (1.f / 256.f) + 1e-5f);
  float4 gg = ((const float4*)g)[lane], bb = ((const float4*)b)[lane];
  float4 r;
  r.x = eluf(dx * rstd * gg.x + bb.x);
  r.y = eluf(dy * rstd * gg.y + bb.y);
  r.z = eluf(dz * rstd * gg.z + bb.z);
  r.w = eluf(dw * rstd * gg.w + bb.w);
  row[lane] = r;
}

// ---------- LayerNorm(+ELU) D=64, in place: wave per node ----------
__global__ __launch_bounds__(256) void ln_elu_64(float* __restrict__ x,
                                                 const float* __restrict__ g,
                                                 const float* __restrict__ b) {
  int node = (int)((blockIdx.x * (size_t)blockDim.x + threadIdx.x) >> 6);
  int lane = threadIdx.x & 63;
  if (node >= NN) return;
  float v = x[(size_t)node * 64 + lane];
  float s = v;
#pragma unroll
  for (int o = 1; o < 64; o <<= 1) s += __shfl_xor(s, o);
  float mean = s * (1.f / 64.f);
  float dv = v - mean;
  float q = dv * dv;
#pragma unroll
  for (int o = 1; o < 64; o <<= 1) q += __shfl_xor(q, o);
  float rstd = rsqrtf(q * (1.f / 64.f) + 1e-5f);
  x[(size_t)node * 64 + lane] = eluf(dv * rstd * g[lane] + b[lane]);
}

// ---------- layer3 epilogue: mean over heads then LN over 32 dims ----------
__global__ __launch_bounds__(256) void ln3_kernel(const float* __restrict__ agg,  // [N,64]
                                                  const float* __restrict__ g,
                                                  const float* __restrict__ b,
                                                  float* __restrict__ out) {  // [N,32]
  int wv = (int)((blockIdx.x * (size_t)blockDim.x + threadIdx.x) >> 6);
  int lane = threadIdx.x & 63;
  int node = wv * 2 + (lane >> 5);
  int c = lane & 31;
  if (node >= NN) return;
  float y = 0.5f * (agg[(size_t)node * 64 + c] + agg[(size_t)node * 64 + 32 + c]);
  float s = y;
#pragma unroll
  for (int o = 1; o < 32; o <<= 1) s += __shfl_xor(s, o);
  float mean = s * (1.f / 32.f);
  float dy = y - mean;
  float q = dy * dy;
#pragma unroll
  for (int o = 1; o < 32; o <<= 1) q += __shfl_xor(q, o);
  float rstd = rsqrtf(q * (1.f / 32.f) + 1e-5f);
  out[(size_t)node * 32 + c] = dy * rstd * g[c] + b[c];
}

extern "C" void kernel_launch(void* const* d_in, const int* in_sizes, int n_in,
                              void* d_out, int out_size, void* d_ws, size_t ws_size,
                              hipStream_t stream) {
  const float* x    = (const float*)d_in[0];
  const int*   ei   = (const int*)d_in[1];
  const float* W1   = (const float*)d_in[2];
  const float* Wh1a = (const float*)d_in[3];
  const float* bh1a = (const float*)d_in[4];
  const float* Wh2a = (const float*)d_in[5];
  const float* bh2a = (const float*)d_in[6];
  const float* g1   = (const float*)d_in[7];
  const float* b1   = (const float*)d_in[8];
  const float* W2   = (const float*)d_in[9];
  const float* Wh1b = (const float*)d_in[10];
  const float* bh1b = (const float*)d_in[11];
  const float* Wh2b = (const float*)d_in[12];
  const float* bh2b = (const float*)d_in[13];
  const float* g2   = (const float*)d_in[14];
  const float* b2   = (const float*)d_in[15];
  const float* W3   = (const float*)d_in[16];
  const float* Wh1c = (const float*)d_in[17];
  const float* bh1c = (const float*)d_in[18];
  const float* Wh2c = (const float*)d_in[19];
  const float* bh2c = (const float*)d_in[20];
  const float* g3   = (const float*)d_in[21];
  const float* b3   = (const float*)d_in[22];

  float* out  = (float*)d_out;
  float* o_x3 = out;                           // N*32
  float* o_h1 = out + (size_t)NN * 32;         // N*64
  float* o_h2 = o_h1 + (size_t)NN * 64;        // N*64
  float* o_h3 = o_h2 + (size_t)NN * 64;        // N*64
  float* o_al = o_h3 + (size_t)NN * 64;        // EPN*2  (also used as logit scratch)

  float* ws  = (float*)d_ws;
  float* A   = ws;                             // N*256 (xt buffer)
  float* Bb  = ws + (size_t)NN * 256;          // N*256 (agg / x buffer)
  int* cnt    = (int*)(Bb + (size_t)NN * 256); // NN
  int* rowptr = cnt + NN;                      // NN+1
  int* fill   = rowptr + NN + 1;               // NN
  int* eids   = fill + NN;                     // EPN

  dim3 blk(256);
  int gEdges = (EPN + 255) / 256;
  int gNodeW = (NN * 64 + 255) / 256;
  int gLn3 = ((NN / 2) * 64) / 256;
  int gRows = (NN + 63) / 64;

  // ---------------- CSR by dst (shared by all 3 layers) ----------------
  hipMemsetAsync(cnt, 0, (size_t)NN * 4, stream);
  hist_kernel<<<gEdges, blk, 0, stream>>>(ei, cnt);
  scan_kernel<<<1, 1024, 0, stream>>>(cnt, rowptr, fill);
  scatter_kernel<<<gEdges, blk, 0, stream>>>(ei, fill, eids);

  // ---------------- Layer 1: 512 -> 2x128 (concat) ----------------
  gemm_f32<<<dim3(4, gRows), blk, 0, stream>>>(x, W1, A, NN, 256, 512);
  aux_head<128><<<2048, 128, 0, stream>>>(A, Wh1a, bh1a, Wh2a, bh2a, o_h1, 1.0f);
  gat_node_256<<<gNodeW, blk, 0, stream>>>(A, ei, rowptr, eids, o_al, Bb);
  ln_elu_256<<<gNodeW, blk, 0, stream>>>(Bb, g1, b1);

  // ---------------- Layer 2: 256 -> 2x32 (concat) ----------------
  gemm_f32<<<dim3(1, gRows), blk, 0, stream>>>(Bb, W2, A, NN, 64, 256);
  aux_head<32><<<2048, 128, 0, stream>>>(A, Wh1b, bh1b, Wh2b, bh2b, o_h2, 0.5f);
  gat_node_64<<<gNodeW, blk, 0, stream>>>(A, ei, rowptr, eids, o_al, Bb, nullptr);
  ln_elu_64<<<gNodeW, blk, 0, stream>>>(Bb, g2, b2);

  // ---------------- Layer 3: 64 -> 2x32 (mean) ----------------
  gemm_f32<<<dim3(1, gRows), blk, 0, stream>>>(Bb, W3, A, NN, 64, 64);
  aux_head<32><<<2048, 128, 0, stream>>>(A, Wh1c, bh1c, Wh2c, bh2c, o_h3, 1.0f);
  gat_node_64<<<gNodeW, blk, 0, stream>>>(A, ei, rowptr, eids, o_al, Bb, o_al);
  ln3_kernel<<<gLn3, blk, 0, stream>>>(Bb, g3, b3, o_x3);
}

// Round 3
// 1110.140 us; speedup vs baseline: 4.0198x; 1.4408x over previous
//
#include <hip/hip_runtime.h>

#define NN 50000
#define EE 800000
#define EPN 850000   // EE + NN (self loops appended)

typedef __attribute__((ext_vector_type(8))) short bf16x8;
typedef __attribute__((ext_vector_type(4))) float f32x4;

// ---------- helpers ----------
__device__ __forceinline__ float eluf(float v) { return v > 0.f ? v : expm1f(v); }
__device__ __forceinline__ unsigned short f2bf(float f) {
  unsigned u = __float_as_uint(f);
  unsigned r = (u + 0x7FFFu + ((u >> 16) & 1u)) >> 16;
  return (unsigned short)r;
}
__device__ __forceinline__ float bf2f(unsigned short b) {
  return __uint_as_float(((unsigned)b) << 16);
}

// ---------- MFMA bf16x3 GEMM (f32-grade accuracy): C[M,N] = A[M,K]@B[K,N] ----------
// block tile 64(M) x 128(N), 4 waves stacked in M, K-step 32.
__global__ __launch_bounds__(256) void gemm_mfma_bf16x3(const float* __restrict__ A,
                                                        const float* __restrict__ B,
                                                        float* __restrict__ C,
                                                        int M, int N, int K) {
  __shared__ unsigned short Ah[64 * 40], Al[64 * 40];
  __shared__ unsigned short Bh[128 * 40], Bl[128 * 40];
  int tid = threadIdx.x;
  int wave = tid >> 6, lane = tid & 63;
  int l15 = lane & 15, l4 = lane >> 4;
  int row0 = blockIdx.y * 64, col0 = blockIdx.x * 128;

  f32x4 acc[8];
#pragma unroll
  for (int t = 0; t < 8; ++t) acc[t] = (f32x4){0.f, 0.f, 0.f, 0.f};

  int ar = tid >> 2;        // A row 0..63
  int ak = (tid & 3) * 8;   // A k-base
  int bc = tid >> 1;        // B col 0..127
  int bk = (tid & 1) * 16;  // B k-base

  for (int k0 = 0; k0 < K; k0 += 32) {
    // ---- stage A (64 x 32 f32 -> hi/lo bf16) ----
    {
      float v[8];
      int grow = row0 + ar;
      if (grow < M) {
        float4 p0 = *(const float4*)&A[(size_t)grow * K + k0 + ak];
        float4 p1 = *(const float4*)&A[(size_t)grow * K + k0 + ak + 4];
        v[0] = p0.x; v[1] = p0.y; v[2] = p0.z; v[3] = p0.w;
        v[4] = p1.x; v[5] = p1.y; v[6] = p1.z; v[7] = p1.w;
      } else {
#pragma unroll
        for (int i = 0; i < 8; ++i) v[i] = 0.f;
      }
      bf16x8 hv, lv;
#pragma unroll
      for (int i = 0; i < 8; ++i) {
        unsigned short h = f2bf(v[i]);
        hv[i] = (short)h;
        lv[i] = (short)f2bf(v[i] - bf2f(h));
      }
      *(bf16x8*)&Ah[ar * 40 + ak] = hv;
      *(bf16x8*)&Al[ar * 40 + ak] = lv;
    }
    // ---- stage B (32 x 128 f32 -> transposed hi/lo bf16 [col][k]) ----
    {
      bf16x8 hv0, lv0, hv1, lv1;
#pragma unroll
      for (int i = 0; i < 8; ++i) {
        float v = B[(size_t)(k0 + bk + i) * N + col0 + bc];
        unsigned short h = f2bf(v);
        hv0[i] = (short)h;
        lv0[i] = (short)f2bf(v - bf2f(h));
      }
#pragma unroll
      for (int i = 0; i < 8; ++i) {
        float v = B[(size_t)(k0 + bk + 8 + i) * N + col0 + bc];
        unsigned short h = f2bf(v);
        hv1[i] = (short)h;
        lv1[i] = (short)f2bf(v - bf2f(h));
      }
      *(bf16x8*)&Bh[bc * 40 + bk] = hv0;
      *(bf16x8*)&Bh[bc * 40 + bk + 8] = hv1;
      *(bf16x8*)&Bl[bc * 40 + bk] = lv0;
      *(bf16x8*)&Bl[bc * 40 + bk + 8] = lv1;
    }
    __syncthreads();
    // ---- MFMA: wave computes rows [16*wave, 16*wave+16) x all 128 cols ----
    bf16x8 a_h = *(const bf16x8*)&Ah[(wave * 16 + l15) * 40 + l4 * 8];
    bf16x8 a_l = *(const bf16x8*)&Al[(wave * 16 + l15) * 40 + l4 * 8];
#pragma unroll
    for (int t = 0; t < 8; ++t) {
      bf16x8 b_h = *(const bf16x8*)&Bh[(t * 16 + l15) * 40 + l4 * 8];
      bf16x8 b_l = *(const bf16x8*)&Bl[(t * 16 + l15) * 40 + l4 * 8];
      acc[t] = __builtin_amdgcn_mfma_f32_16x16x32_bf16(a_h, b_h, acc[t], 0, 0, 0);
      acc[t] = __builtin_amdgcn_mfma_f32_16x16x32_bf16(a_h, b_l, acc[t], 0, 0, 0);
      acc[t] = __builtin_amdgcn_mfma_f32_16x16x32_bf16(a_l, b_h, acc[t], 0, 0, 0);
    }
    __syncthreads();
  }
  // ---- epilogue: D[row=(lane>>4)*4+r][col=lane&15] per 16x16 tile ----
#pragma unroll
  for (int t = 0; t < 8; ++t) {
#pragma unroll
    for (int r = 0; r < 4; ++r) {
      int grow = row0 + wave * 16 + l4 * 4 + r;
      if (grow < M) C[(size_t)grow * N + col0 + t * 16 + l15] = acc[t][r];
    }
  }
}

// ---------- generic f32 GEMM (layers 2,3): C[M,N]=A[M,K]@B[K,N]; N%64==0,K%16==0 ----------
__global__ __launch_bounds__(256) void gemm_f32(const float* __restrict__ A,
                                                const float* __restrict__ B,
                                                float* __restrict__ C,
                                                int M, int N, int K) {
  __shared__ float As[16][65];
  __shared__ float Bs[16][64];
  int tid = threadIdx.x;
  int row0 = blockIdx.y * 64, col0 = blockIdx.x * 64;
  int tx = tid & 15, ty = tid >> 4;
  float acc[4][4] = {};
  for (int k0 = 0; k0 < K; k0 += 16) {
    {
      int r = tid >> 2;
      int kk = (tid & 3) * 4;
      float4 av = make_float4(0.f, 0.f, 0.f, 0.f);
      if (row0 + r < M) av = *(const float4*)&A[(size_t)(row0 + r) * K + k0 + kk];
      As[kk + 0][r] = av.x; As[kk + 1][r] = av.y; As[kk + 2][r] = av.z; As[kk + 3][r] = av.w;
    }
    {
      int kk = tid >> 4;
      int c = (tid & 15) * 4;
      *(float4*)&Bs[kk][c] = *(const float4*)&B[(size_t)(k0 + kk) * N + col0 + c];
    }
    __syncthreads();
#pragma unroll
    for (int k = 0; k < 16; ++k) {
      float a[4], b[4];
#pragma unroll
      for (int i = 0; i < 4; ++i) a[i] = As[k][ty * 4 + i];
#pragma unroll
      for (int j = 0; j < 4; ++j) b[j] = Bs[k][tx * 4 + j];
#pragma unroll
      for (int i = 0; i < 4; ++i)
#pragma unroll
        for (int j = 0; j < 4; ++j) acc[i][j] += a[i] * b[j];
    }
    __syncthreads();
  }
#pragma unroll
  for (int i = 0; i < 4; ++i) {
    int r = row0 + ty * 4 + i;
    if (r < M)
      *(float4*)&C[(size_t)r * N + col0 + tx * 4] =
          make_float4(acc[i][0], acc[i][1], acc[i][2], acc[i][3]);
  }
}

// ---------- CSR build ----------
__global__ __launch_bounds__(256) void hist_kernel(const int* __restrict__ ei,
                                                   int* __restrict__ cnt) {
  int e = blockIdx.x * 256 + threadIdx.x;
  if (e >= EPN) return;
  int d = (e < EE) ? ei[EE + e] : e - EE;
  atomicAdd(&cnt[d], 1);
}

__global__ __launch_bounds__(1024) void scan_kernel(const int* __restrict__ cnt,
                                                    int* __restrict__ rowptr,
                                                    int* __restrict__ fill) {
  __shared__ int lds[1024];
  __shared__ int carry_s;
  int t = threadIdx.x;
  if (t == 0) { carry_s = 0; rowptr[0] = 0; }
  __syncthreads();
  for (int base = 0; base < NN; base += 1024) {
    int idx = base + t;
    int v = (idx < NN) ? cnt[idx] : 0;
    lds[t] = v;
    __syncthreads();
    for (int off = 1; off < 1024; off <<= 1) {
      int add = (t >= off) ? lds[t - off] : 0;
      __syncthreads();
      lds[t] += add;
      __syncthreads();
    }
    int inc = lds[t] + carry_s;
    if (idx < NN) { rowptr[idx + 1] = inc; fill[idx] = inc - v; }
    __syncthreads();
    if (t == 1023) carry_s = inc;
    __syncthreads();
  }
}

__global__ __launch_bounds__(256) void scatter_kernel(const int* __restrict__ ei,
                                                      int* __restrict__ fill,
                                                      int* __restrict__ eids) {
  int e = blockIdx.x * 256 + threadIdx.x;
  if (e >= EPN) return;
  int d = (e < EE) ? ei[EE + e] : e - EE;
  int pos = atomicAdd(&fill[d], 1);
  eids[pos] = e;
}

// ---------- ONLINE single-pass GAT edge phase, D=256 (H=2, C=128) ----------
__global__ __launch_bounds__(256) void gat_online_256(const float* __restrict__ xt,
                                                      const int* __restrict__ ei,
                                                      const int* __restrict__ rowptr,
                                                      const int* __restrict__ eids,
                                                      float* __restrict__ outb) {
  int node = (int)((blockIdx.x * (size_t)blockDim.x + threadIdx.x) >> 6);
  int lane = threadIdx.x & 63;
  if (node >= NN) return;
  int start = rowptr[node], end = rowptr[node + 1];
  float4 dstv = ((const float4*)(xt + (size_t)node * 256))[lane];
  float m = -1e30f, s = 0.f;
  float4 acc = make_float4(0.f, 0.f, 0.f, 0.f);
  for (int i = start; i < end; ++i) {
    int e = eids[i];
    int src = (e < EE) ? ei[e] : e - EE;
    float4 a = ((const float4*)(xt + (size_t)src * 256))[lane];
    float p = a.x * dstv.x + a.y * dstv.y + a.z * dstv.z + a.w * dstv.w;
#pragma unroll
    for (int o = 1; o < 32; o <<= 1) p += __shfl_xor(p, o);  // per-half reduce
    p *= 0.08838834764831843f;  // 1/sqrt(128)
    float mn = fmaxf(m, p);
    float sc = expf(m - mn);
    float w = expf(p - mn);
    s = s * sc + w;
    acc.x = acc.x * sc + w * a.x;
    acc.y = acc.y * sc + w * a.y;
    acc.z = acc.z * sc + w * a.z;
    acc.w = acc.w * sc + w * a.w;
    m = mn;
  }
  float inv = 1.f / (s + 1e-16f);
  acc.x *= inv; acc.y *= inv; acc.z *= inv; acc.w *= inv;
  ((float4*)(outb + (size_t)node * 256))[lane] = acc;
}

// ---------- ONLINE single-pass GAT edge phase, D=64 (H=2, C=32) ----------
// Optionally records raw logits + final (m,s) per node for the alpha fix-up.
__global__ __launch_bounds__(256) void gat_online_64(const float* __restrict__ xt,
                                                     const int* __restrict__ ei,
                                                     const int* __restrict__ rowptr,
                                                     const int* __restrict__ eids,
                                                     float* __restrict__ outb,
                                                     float* __restrict__ logit_out,
                                                     float* __restrict__ mbuf,
                                                     float* __restrict__ sbuf) {
  int node = (int)((blockIdx.x * (size_t)blockDim.x + threadIdx.x) >> 6);
  int lane = threadIdx.x & 63;
  if (node >= NN) return;
  int half = lane >> 5, l32 = lane & 31;
  int start = rowptr[node], end = rowptr[node + 1];
  float dv = xt[(size_t)node * 64 + lane];
  float m = -1e30f, s = 0.f, acc = 0.f;
  for (int i = start; i < end; ++i) {
    int e = eids[i];
    int src = (e < EE) ? ei[e] : e - EE;
    float a = xt[(size_t)src * 64 + lane];
    float p = a * dv;
#pragma unroll
    for (int o = 1; o < 32; o <<= 1) p += __shfl_xor(p, o);
    p *= 0.17677669529663687f;  // 1/sqrt(32)
    if (logit_out && l32 == 0) logit_out[(size_t)e * 2 + half] = p;
    float mn = fmaxf(m, p);
    float sc = expf(m - mn);
    float w = expf(p - mn);
    s = s * sc + w;
    acc = acc * sc + w * a;
    m = mn;
  }
  float inv = 1.f / (s + 1e-16f);
  outb[(size_t)node * 64 + lane] = acc * inv;
  if (mbuf && l32 == 0) {
    mbuf[(size_t)node * 2 + half] = m;
    sbuf[(size_t)node * 2 + half] = s;
  }
}

// ---------- alpha fix-up: logit -> exp(logit - m)/ (s+1e-16), in place ----------
__global__ __launch_bounds__(256) void alpha_fix(float* __restrict__ al,
                                                 const int* __restrict__ ei,
                                                 const float* __restrict__ mbuf,
                                                 const float* __restrict__ sbuf) {
  size_t i = blockIdx.x * (size_t)blockDim.x + threadIdx.x;
  if (i >= (size_t)EPN * 2) return;
  int e = (int)(i >> 1), h = (int)(i & 1);
  int d = (e < EE) ? ei[EE + e] : e - EE;
  al[i] = expf(al[i] - mbuf[(size_t)d * 2 + h]) / (sbuf[(size_t)d * 2 + h] + 1e-16f);
}

// ---------- aux class head: h = (elu(xt@Wh1+bh1))@Wh2+bh2, per head ----------
template <int C>
__global__ __launch_bounds__(128) void aux_head(const float* __restrict__ xt,   // [N, 2*C]
                                                const float* __restrict__ Wh1,  // [C,64]
                                                const float* __restrict__ bh1,  // [64]
                                                const float* __restrict__ Wh2,  // [64,32]
                                                const float* __restrict__ bh2,  // [32]
                                                float* __restrict__ hout,       // [N,64]
                                                float scale) {
  __shared__ float w1s[C * 64];
  __shared__ float w2s[64 * 32];
  __shared__ float b1s[64], b2s[32];
  __shared__ float xrow[2 * C];
  __shared__ float hid[128];
  int tid = threadIdx.x;
  for (int i = tid; i < C * 64; i += 128) w1s[i] = Wh1[i];
  for (int i = tid; i < 64 * 32; i += 128) w2s[i] = Wh2[i];
  if (tid < 64) b1s[tid] = bh1[tid];
  if (tid < 32) b2s[tid] = bh2[tid];
  __syncthreads();
  for (int n = blockIdx.x; n < NN; n += gridDim.x) {
    for (int i = tid; i < 2 * C; i += 128) xrow[i] = xt[(size_t)n * 2 * C + i];
    __syncthreads();
    int h = tid >> 6, j = tid & 63;
    float acc = b1s[j];
#pragma unroll 8
    for (int c = 0; c < C; ++c) acc += xrow[h * C + c] * w1s[c * 64 + j];
    hid[tid] = eluf(acc);
    __syncthreads();
    if (tid < 64) {
      int hh = tid >> 5, k = tid & 31;
      float o = b2s[k];
#pragma unroll
      for (int jj = 0; jj < 64; ++jj) o += hid[hh * 64 + jj] * w2s[jj * 32 + k];
      hout[(size_t)n * 64 + tid] = o * scale;
    }
    __syncthreads();
  }
}

// ---------- LayerNorm(+ELU) D=256, in place: wave per node ----------
__global__ __launch_bounds__(256) void ln_elu_256(float* __restrict__ x,
                                                  const float* __restrict__ g,
                                                  const float* __restrict__ b) {
  int node = (int)((blockIdx.x * (size_t)blockDim.x + threadIdx.x) >> 6);
  int lane = threadIdx.x & 63;
  if (node >= NN) return;
  float4* row = (float4*)(x + (size_t)node * 256);
  float4 v = row[lane];
  float s = v.x + v.y + v.z + v.w;
#pragma unroll
  for (int o = 1; o < 64; o <<= 1) s += __shfl_xor(s, o);
  float mean = s * (1.f / 256.f);
  float dx = v.x - mean, dy = v.y - mean, dz = v.z - mean, dw = v.w - mean;
  float q = dx * dx + dy * dy + dz * dz + dw * dw;
#pragma unroll
  for (int o = 1; o < 64; o <<= 1) q += __shfl_xor(q, o);
  float rstd = rsqrtf(q * (1.f / 256.f) + 1e-5f);
  float4 gg = ((const float4*)g)[lane], bb = ((const float4*)b)[lane];
  float4 r;
  r.x = eluf(dx * rstd * gg.x + bb.x);
  r.y = eluf(dy * rstd * gg.y + bb.y);
  r.z = eluf(dz * rstd * gg.z + bb.z);
  r.w = eluf(dw * rstd * gg.w + bb.w);
  row[lane] = r;
}

// ---------- LayerNorm(+ELU) D=64, in place: wave per node ----------
__global__ __launch_bounds__(256) void ln_elu_64(float* __restrict__ x,
                                                 const float* __restrict__ g,
                                                 const float* __restrict__ b) {
  int node = (int)((blockIdx.x * (size_t)blockDim.x + threadIdx.x) >> 6);
  int lane = threadIdx.x & 63;
  if (node >= NN) return;
  float v = x[(size_t)node * 64 + lane];
  float s = v;
#pragma unroll
  for (int o = 1; o < 64; o <<= 1) s += __shfl_xor(s, o);
  float mean = s * (1.f / 64.f);
  float dv = v - mean;
  float q = dv * dv;
#pragma unroll
  for (int o = 1; o < 64; o <<= 1) q += __shfl_xor(q, o);
  float rstd = rsqrtf(q * (1.f / 64.f) + 1e-5f);
  x[(size_t)node * 64 + lane] = eluf(dv * rstd * g[lane] + b[lane]);
}

// ---------- layer3 epilogue: mean over heads then LN over 32 dims ----------
__global__ __launch_bounds__(256) void ln3_kernel(const float* __restrict__ agg,  // [N,64]
                                                  const float* __restrict__ g,
                                                  const float* __restrict__ b,
                                                  float* __restrict__ out) {  // [N,32]
  int wv = (int)((blockIdx.x * (size_t)blockDim.x + threadIdx.x) >> 6);
  int lane = threadIdx.x & 63;
  int node = wv * 2 + (lane >> 5);
  int c = lane & 31;
  if (node >= NN) return;
  float y = 0.5f * (agg[(size_t)node * 64 + c] + agg[(size_t)node * 64 + 32 + c]);
  float s = y;
#pragma unroll
  for (int o = 1; o < 32; o <<= 1) s += __shfl_xor(s, o);
  float mean = s * (1.f / 32.f);
  float dy = y - mean;
  float q = dy * dy;
#pragma unroll
  for (int o = 1; o < 32; o <<= 1) q += __shfl_xor(q, o);
  float rstd = rsqrtf(q * (1.f / 32.f) + 1e-5f);
  out[(size_t)node * 32 + c] = dy * rstd * g[c] + b[c];
}

extern "C" void kernel_launch(void* const* d_in, const int* in_sizes, int n_in,
                              void* d_out, int out_size, void* d_ws, size_t ws_size,
                              hipStream_t stream) {
  const float* x    = (const float*)d_in[0];
  const int*   ei   = (const int*)d_in[1];
  const float* W1   = (const float*)d_in[2];
  const float* Wh1a = (const float*)d_in[3];
  const float* bh1a = (const float*)d_in[4];
  const float* Wh2a = (const float*)d_in[5];
  const float* bh2a = (const float*)d_in[6];
  const float* g1   = (const float*)d_in[7];
  const float* b1   = (const float*)d_in[8];
  const float* W2   = (const float*)d_in[9];
  const float* Wh1b = (const float*)d_in[10];
  const float* bh1b = (const float*)d_in[11];
  const float* Wh2b = (const float*)d_in[12];
  const float* bh2b = (const float*)d_in[13];
  const float* g2   = (const float*)d_in[14];
  const float* b2   = (const float*)d_in[15];
  const float* W3   = (const float*)d_in[16];
  const float* Wh1c = (const float*)d_in[17];
  const float* bh1c = (const float*)d_in[18];
  const float* Wh2c = (const float*)d_in[19];
  const float* bh2c = (const float*)d_in[20];
  const float* g3   = (const float*)d_in[21];
  const float* b3   = (const float*)d_in[22];

  float* out  = (float*)d_out;
  float* o_x3 = out;                           // N*32
  float* o_h1 = out + (size_t)NN * 32;         // N*64
  float* o_h2 = o_h1 + (size_t)NN * 64;        // N*64
  float* o_h3 = o_h2 + (size_t)NN * 64;        // N*64
  float* o_al = o_h3 + (size_t)NN * 64;        // EPN*2 (logits then alpha)

  float* ws  = (float*)d_ws;
  float* A   = ws;                             // N*256 (xt buffer)
  float* Bb  = ws + (size_t)NN * 256;          // N*256 (agg / x buffer)
  int* cnt    = (int*)(Bb + (size_t)NN * 256); // NN
  int* rowptr = cnt + NN;                      // NN+1
  int* fill   = rowptr + NN + 1;               // NN
  int* eids   = fill + NN;                     // EPN
  float* mbuf = (float*)(eids + EPN);          // NN*2
  float* sbuf = mbuf + (size_t)NN * 2;         // NN*2

  dim3 blk(256);
  int gEdges = (EPN + 255) / 256;
  int gNodeW = (NN * 64 + 255) / 256;
  int gLn3 = ((NN / 2) * 64) / 256;
  int gRows = (NN + 63) / 64;
  int gPairs = (int)(((size_t)EPN * 2 + 255) / 256);

  // ---------------- CSR by dst (shared by all 3 layers) ----------------
  hipMemsetAsync(cnt, 0, (size_t)NN * 4, stream);
  hist_kernel<<<gEdges, blk, 0, stream>>>(ei, cnt);
  scan_kernel<<<1, 1024, 0, stream>>>(cnt, rowptr, fill);
  scatter_kernel<<<gEdges, blk, 0, stream>>>(ei, fill, eids);

  // ---------------- Layer 1: 512 -> 2x128 (concat) ----------------
  gemm_mfma_bf16x3<<<dim3(2, gRows), blk, 0, stream>>>(x, W1, A, NN, 256, 512);
  aux_head<128><<<2048, 128, 0, stream>>>(A, Wh1a, bh1a, Wh2a, bh2a, o_h1, 1.0f);
  gat_online_256<<<gNodeW, blk, 0, stream>>>(A, ei, rowptr, eids, Bb);
  ln_elu_256<<<gNodeW, blk, 0, stream>>>(Bb, g1, b1);

  // ---------------- Layer 2: 256 -> 2x32 (concat) ----------------
  gemm_f32<<<dim3(1, gRows), blk, 0, stream>>>(Bb, W2, A, NN, 64, 256);
  aux_head<32><<<2048, 128, 0, stream>>>(A, Wh1b, bh1b, Wh2b, bh2b, o_h2, 0.5f);
  gat_online_64<<<gNodeW, blk, 0, stream>>>(A, ei, rowptr, eids, Bb, nullptr, nullptr, nullptr);
  ln_elu_64<<<gNodeW, blk, 0, stream>>>(Bb, g2, b2);

  // ---------------- Layer 3: 64 -> 2x32 (mean) ----------------
  gemm_f32<<<dim3(1, gRows), blk, 0, stream>>>(Bb, W3, A, NN, 64, 64);
  aux_head<32><<<2048, 128, 0, stream>>>(A, Wh1c, bh1c, Wh2c, bh2c, o_h3, 1.0f);
  gat_online_64<<<gNodeW, blk, 0, stream>>>(A, ei, rowptr, eids, Bb, o_al, mbuf, sbuf);
  alpha_fix<<<gPairs, blk, 0, stream>>>(o_al, ei, mbuf, sbuf);
  ln3_kernel<<<gLn3, blk, 0, stream>>>(Bb, g3, b3, o_x3);
}

// Round 4
// 905.498 us; speedup vs baseline: 4.9282x; 1.2260x over previous
//
#include <hip/hip_runtime.h>

#define NN 50000
#define EE 800000
#define EPN 850000   // EE + NN (self loops appended)

typedef __attribute__((ext_vector_type(8))) short bf16x8;
typedef __attribute__((ext_vector_type(4))) float f32x4;

// ---------- helpers ----------
__device__ __forceinline__ float eluf(float v) { return v > 0.f ? v : expm1f(v); }
__device__ __forceinline__ unsigned short f2bf(float f) {
  unsigned u = __float_as_uint(f);
  unsigned r = (u + 0x7FFFu + ((u >> 16) & 1u)) >> 16;
  return (unsigned short)r;
}
__device__ __forceinline__ float bf2f(unsigned short b) {
  return __uint_as_float(((unsigned)b) << 16);
}

// ---------- MFMA bf16x3 GEMM (f32-grade): C[M,N]=A[M,K]@B[K,N] ----------
// block tile 64(M) x NT*16(N), 4 waves stacked in M, K-step 32. K%32==0.
template <int NT>
__global__ __launch_bounds__(256) void gemm_mfma(const float* __restrict__ A,
                                                 const float* __restrict__ B,
                                                 float* __restrict__ C,
                                                 int M, int N, int K) {
  __shared__ unsigned short Ah[64 * 40], Al[64 * 40];
  __shared__ unsigned short Bh[NT * 16 * 40], Bl[NT * 16 * 40];
  int tid = threadIdx.x;
  int wave = tid >> 6, lane = tid & 63;
  int l15 = lane & 15, l4 = lane >> 4;
  int row0 = blockIdx.y * 64, col0 = blockIdx.x * (NT * 16);

  f32x4 acc[NT];
#pragma unroll
  for (int t = 0; t < NT; ++t) acc[t] = (f32x4){0.f, 0.f, 0.f, 0.f};

  int ar = tid >> 2;        // A row 0..63
  int ak = (tid & 3) * 8;   // A k-base
  constexpr int TPC = 256 / (NT * 16);  // threads per B col
  constexpr int NK = 32 / TPC;          // k elems per thread
  int bc = tid / TPC;
  int bk = (tid % TPC) * NK;

  for (int k0 = 0; k0 < K; k0 += 32) {
    // ---- stage A (64 x 32 f32 -> hi/lo bf16) ----
    {
      float v[8];
      int grow = row0 + ar;
      if (grow < M) {
        float4 p0 = *(const float4*)&A[(size_t)grow * K + k0 + ak];
        float4 p1 = *(const float4*)&A[(size_t)grow * K + k0 + ak + 4];
        v[0] = p0.x; v[1] = p0.y; v[2] = p0.z; v[3] = p0.w;
        v[4] = p1.x; v[5] = p1.y; v[6] = p1.z; v[7] = p1.w;
      } else {
#pragma unroll
        for (int i = 0; i < 8; ++i) v[i] = 0.f;
      }
      bf16x8 hv, lv;
#pragma unroll
      for (int i = 0; i < 8; ++i) {
        unsigned short h = f2bf(v[i]);
        hv[i] = (short)h;
        lv[i] = (short)f2bf(v[i] - bf2f(h));
      }
      *(bf16x8*)&Ah[ar * 40 + ak] = hv;
      *(bf16x8*)&Al[ar * 40 + ak] = lv;
    }
    // ---- stage B (32 x NT*16 f32 -> transposed hi/lo bf16 [col][k]) ----
    {
#pragma unroll
      for (int i = 0; i < NK; ++i) {
        float v = B[(size_t)(k0 + bk + i) * N + col0 + bc];
        unsigned short h = f2bf(v);
        Bh[bc * 40 + bk + i] = h;
        Bl[bc * 40 + bk + i] = f2bf(v - bf2f(h));
      }
    }
    __syncthreads();
    bf16x8 a_h = *(const bf16x8*)&Ah[(wave * 16 + l15) * 40 + l4 * 8];
    bf16x8 a_l = *(const bf16x8*)&Al[(wave * 16 + l15) * 40 + l4 * 8];
#pragma unroll
    for (int t = 0; t < NT; ++t) {
      bf16x8 b_h = *(const bf16x8*)&Bh[(t * 16 + l15) * 40 + l4 * 8];
      bf16x8 b_l = *(const bf16x8*)&Bl[(t * 16 + l15) * 40 + l4 * 8];
      acc[t] = __builtin_amdgcn_mfma_f32_16x16x32_bf16(a_h, b_h, acc[t], 0, 0, 0);
      acc[t] = __builtin_amdgcn_mfma_f32_16x16x32_bf16(a_h, b_l, acc[t], 0, 0, 0);
      acc[t] = __builtin_amdgcn_mfma_f32_16x16x32_bf16(a_l, b_h, acc[t], 0, 0, 0);
    }
    __syncthreads();
  }
#pragma unroll
  for (int t = 0; t < NT; ++t) {
#pragma unroll
    for (int r = 0; r < 4; ++r) {
      int grow = row0 + wave * 16 + l4 * 4 + r;
      if (grow < M) C[(size_t)grow * N + col0 + t * 16 + l15] = acc[t][r];
    }
  }
}

// ---------- fused aux head via MFMA: hout = (elu(X2@Wh1+bh1))@Wh2+bh2 ----------
// X2 = xt viewed [2N, C]; 64 rows/block, 4 waves x 16 rows.
template <int C>
__global__ __launch_bounds__(256) void aux_mfma(const float* __restrict__ xt,
                                                const float* __restrict__ Wh1,  // [C,64]
                                                const float* __restrict__ bh1,  // [64]
                                                const float* __restrict__ Wh2,  // [64,32]
                                                const float* __restrict__ bh2,  // [32]
                                                float* __restrict__ hout,       // [N,64]
                                                float scale) {
  constexpr int KS = C / 32;
  constexpr int LDB = C + 8;
  __shared__ unsigned short BhS[64 * LDB], BlS[64 * LDB];
  __shared__ float w2s[64 * 32];
  __shared__ float hid[64 * 68];
  int tid = threadIdx.x;
  // stage Wh1 [C,64] -> [col][k] hi/lo
  for (int i = tid; i < C * 64; i += 256) {
    int k = i >> 6, col = i & 63;
    float v = Wh1[i];
    unsigned short h = f2bf(v);
    BhS[col * LDB + k] = h;
    BlS[col * LDB + k] = f2bf(v - bf2f(h));
  }
  for (int i = tid; i < 64 * 32; i += 256) w2s[i] = Wh2[i];
  __syncthreads();

  int w = tid >> 6, lane = tid & 63, l15 = lane & 15, l4 = lane >> 4;
  int gr = blockIdx.x * 64 + w * 16 + l15;  // X2 row this lane owns
  const int M2 = 2 * NN;

  f32x4 acc[4];
#pragma unroll
  for (int t = 0; t < 4; ++t) acc[t] = (f32x4){0.f, 0.f, 0.f, 0.f};

#pragma unroll
  for (int ks = 0; ks < KS; ++ks) {
    bf16x8 ah, al;
    if (gr < M2) {
      const float* p = xt + (size_t)gr * C + ks * 32 + l4 * 8;
      float4 p0 = *(const float4*)p;
      float4 p1 = *(const float4*)(p + 4);
      float v[8] = {p0.x, p0.y, p0.z, p0.w, p1.x, p1.y, p1.z, p1.w};
#pragma unroll
      for (int i = 0; i < 8; ++i) {
        unsigned short h = f2bf(v[i]);
        ah[i] = (short)h;
        al[i] = (short)f2bf(v[i] - bf2f(h));
      }
    } else {
      ah = (bf16x8){0, 0, 0, 0, 0, 0, 0, 0};
      al = ah;
    }
#pragma unroll
    for (int t = 0; t < 4; ++t) {
      bf16x8 b_h = *(const bf16x8*)&BhS[(t * 16 + l15) * LDB + ks * 32 + l4 * 8];
      bf16x8 b_l = *(const bf16x8*)&BlS[(t * 16 + l15) * LDB + ks * 32 + l4 * 8];
      acc[t] = __builtin_amdgcn_mfma_f32_16x16x32_bf16(ah, b_h, acc[t], 0, 0, 0);
      acc[t] = __builtin_amdgcn_mfma_f32_16x16x32_bf16(ah, b_l, acc[t], 0, 0, 0);
      acc[t] = __builtin_amdgcn_mfma_f32_16x16x32_bf16(al, b_h, acc[t], 0, 0, 0);
    }
  }
  // bias + ELU -> hid LDS. C/D layout: row=l4*4+r, col=t*16+l15 (within wave tile)
#pragma unroll
  for (int t = 0; t < 4; ++t) {
    float bb = bh1[t * 16 + l15];
#pragma unroll
    for (int r = 0; r < 4; ++r)
      hid[(w * 16 + l4 * 4 + r) * 68 + t * 16 + l15] = eluf(acc[t][r] + bb);
  }
  __syncthreads();
  // GEMM2 on VALU: lane -> row = w*16+l15, classes l4*8..+7
  float4 o0 = make_float4(0.f, 0.f, 0.f, 0.f), o1 = o0;
  const float* hrow = &hid[(w * 16 + l15) * 68];
#pragma unroll 8
  for (int k = 0; k < 64; ++k) {
    float hv = hrow[k];
    float4 wa = *(const float4*)&w2s[k * 32 + l4 * 8];
    float4 wb = *(const float4*)&w2s[k * 32 + l4 * 8 + 4];
    o0.x += hv * wa.x; o0.y += hv * wa.y; o0.z += hv * wa.z; o0.w += hv * wa.w;
    o1.x += hv * wb.x; o1.y += hv * wb.y; o1.z += hv * wb.z; o1.w += hv * wb.w;
  }
  if (gr < M2) {
    float4 ba = *(const float4*)&bh2[l4 * 8];
    float4 bb = *(const float4*)&bh2[l4 * 8 + 4];
    o0.x = (o0.x + ba.x) * scale; o0.y = (o0.y + ba.y) * scale;
    o0.z = (o0.z + ba.z) * scale; o0.w = (o0.w + ba.w) * scale;
    o1.x = (o1.x + bb.x) * scale; o1.y = (o1.y + bb.y) * scale;
    o1.z = (o1.z + bb.z) * scale; o1.w = (o1.w + bb.w) * scale;
    float* dst = hout + (size_t)(gr >> 1) * 64 + (gr & 1) * 32 + l4 * 8;
    *(float4*)dst = o0;
    *(float4*)(dst + 4) = o1;
  }
}

// ---------- CSR build ----------
__global__ __launch_bounds__(256) void hist_kernel(const int* __restrict__ ei,
                                                   int* __restrict__ cnt) {
  int e = blockIdx.x * 256 + threadIdx.x;
  if (e >= EPN) return;
  int d = (e < EE) ? ei[EE + e] : e - EE;
  atomicAdd(&cnt[d], 1);
}

__global__ __launch_bounds__(1024) void scan_kernel(const int* __restrict__ cnt,
                                                    int* __restrict__ rowptr,
                                                    int* __restrict__ fill) {
  __shared__ int lds[1024];
  __shared__ int carry_s;
  int t = threadIdx.x;
  if (t == 0) { carry_s = 0; rowptr[0] = 0; }
  __syncthreads();
  for (int base = 0; base < NN; base += 1024) {
    int idx = base + t;
    int v = (idx < NN) ? cnt[idx] : 0;
    lds[t] = v;
    __syncthreads();
    for (int off = 1; off < 1024; off <<= 1) {
      int add = (t >= off) ? lds[t - off] : 0;
      __syncthreads();
      lds[t] += add;
      __syncthreads();
    }
    int inc = lds[t] + carry_s;
    if (idx < NN) { rowptr[idx + 1] = inc; fill[idx] = inc - v; }
    __syncthreads();
    if (t == 1023) carry_s = inc;
    __syncthreads();
  }
}

__global__ __launch_bounds__(256) void scatter_kernel(const int* __restrict__ ei,
                                                      int* __restrict__ fill,
                                                      int* __restrict__ eids) {
  int e = blockIdx.x * 256 + threadIdx.x;
  if (e >= EPN) return;
  int d = (e < EE) ? ei[EE + e] : e - EE;
  int pos = atomicAdd(&fill[d], 1);
  eids[pos] = e;
}

// ---------- ONLINE single-pass GAT edge phase, D=256 (H=2, C=128) ----------
__global__ __launch_bounds__(256) void gat_online_256(const float* __restrict__ xt,
                                                      const int* __restrict__ ei,
                                                      const int* __restrict__ rowptr,
                                                      const int* __restrict__ eids,
                                                      float* __restrict__ outb) {
  int node = (int)((blockIdx.x * (size_t)blockDim.x + threadIdx.x) >> 6);
  int lane = threadIdx.x & 63;
  if (node >= NN) return;
  int start = rowptr[node], end = rowptr[node + 1];
  float4 dstv = ((const float4*)(xt + (size_t)node * 256))[lane];
  float m = -1e30f, s = 0.f;
  float4 acc = make_float4(0.f, 0.f, 0.f, 0.f);
  for (int i = start; i < end; ++i) {
    int e = eids[i];
    int src = (e < EE) ? ei[e] : e - EE;
    float4 a = ((const float4*)(xt + (size_t)src * 256))[lane];
    float p = a.x * dstv.x + a.y * dstv.y + a.z * dstv.z + a.w * dstv.w;
#pragma unroll
    for (int o = 1; o < 32; o <<= 1) p += __shfl_xor(p, o);
    p *= 0.08838834764831843f;  // 1/sqrt(128)
    float mn = fmaxf(m, p);
    float sc = expf(m - mn);
    float w = expf(p - mn);
    s = s * sc + w;
    acc.x = acc.x * sc + w * a.x;
    acc.y = acc.y * sc + w * a.y;
    acc.z = acc.z * sc + w * a.z;
    acc.w = acc.w * sc + w * a.w;
    m = mn;
  }
  float inv = 1.f / (s + 1e-16f);
  acc.x *= inv; acc.y *= inv; acc.z *= inv; acc.w *= inv;
  ((float4*)(outb + (size_t)node * 256))[lane] = acc;
}

// ---------- ONLINE single-pass GAT edge phase, D=64 (H=2, C=32) ----------
__global__ __launch_bounds__(256) void gat_online_64(const float* __restrict__ xt,
                                                     const int* __restrict__ ei,
                                                     const int* __restrict__ rowptr,
                                                     const int* __restrict__ eids,
                                                     float* __restrict__ outb,
                                                     float* __restrict__ logit_out,
                                                     float* __restrict__ mbuf,
                                                     float* __restrict__ sbuf) {
  int node = (int)((blockIdx.x * (size_t)blockDim.x + threadIdx.x) >> 6);
  int lane = threadIdx.x & 63;
  if (node >= NN) return;
  int half = lane >> 5, l32 = lane & 31;
  int start = rowptr[node], end = rowptr[node + 1];
  float dv = xt[(size_t)node * 64 + lane];
  float m = -1e30f, s = 0.f, acc = 0.f;
  for (int i = start; i < end; ++i) {
    int e = eids[i];
    int src = (e < EE) ? ei[e] : e - EE;
    float a = xt[(size_t)src * 64 + lane];
    float p = a * dv;
#pragma unroll
    for (int o = 1; o < 32; o <<= 1) p += __shfl_xor(p, o);
    p *= 0.17677669529663687f;  // 1/sqrt(32)
    if (logit_out && l32 == 0) logit_out[(size_t)e * 2 + half] = p;
    float mn = fmaxf(m, p);
    float sc = expf(m - mn);
    float w = expf(p - mn);
    s = s * sc + w;
    acc = acc * sc + w * a;
    m = mn;
  }
  float inv = 1.f / (s + 1e-16f);
  outb[(size_t)node * 64 + lane] = acc * inv;
  if (mbuf && l32 == 0) {
    mbuf[(size_t)node * 2 + half] = m;
    sbuf[(size_t)node * 2 + half] = s;
  }
}

// ---------- alpha fix-up ----------
__global__ __launch_bounds__(256) void alpha_fix(float* __restrict__ al,
                                                 const int* __restrict__ ei,
                                                 const float* __restrict__ mbuf,
                                                 const float* __restrict__ sbuf) {
  size_t i = blockIdx.x * (size_t)blockDim.x + threadIdx.x;
  if (i >= (size_t)EPN * 2) return;
  int e = (int)(i >> 1), h = (int)(i & 1);
  int d = (e < EE) ? ei[EE + e] : e - EE;
  al[i] = expf(al[i] - mbuf[(size_t)d * 2 + h]) / (sbuf[(size_t)d * 2 + h] + 1e-16f);
}

// ---------- LayerNorm(+ELU) D=256, in place ----------
__global__ __launch_bounds__(256) void ln_elu_256(float* __restrict__ x,
                                                  const float* __restrict__ g,
                                                  const float* __restrict__ b) {
  int node = (int)((blockIdx.x * (size_t)blockDim.x + threadIdx.x) >> 6);
  int lane = threadIdx.x & 63;
  if (node >= NN) return;
  float4* row = (float4*)(x + (size_t)node * 256);
  float4 v = row[lane];
  float s = v.x + v.y + v.z + v.w;
#pragma unroll
  for (int o = 1; o < 64; o <<= 1) s += __shfl_xor(s, o);
  float mean = s * (1.f / 256.f);
  float dx = v.x - mean, dy = v.y - mean, dz = v.z - mean, dw = v.w - mean;
  float q = dx * dx + dy * dy + dz * dz + dw * dw;
#pragma unroll
  for (int o = 1; o < 64; o <<= 1) q += __shfl_xor(q, o);
  float rstd = rsqrtf(q * (1.f / 256.f) + 1e-5f);
  float4 gg = ((const float4*)g)[lane], bb = ((const float4*)b)[lane];
  float4 r;
  r.x = eluf(dx * rstd * gg.x + bb.x);
  r.y = eluf(dy * rstd * gg.y + bb.y);
  r.z = eluf(dz * rstd * gg.z + bb.z);
  r.w = eluf(dw * rstd * gg.w + bb.w);
  row[lane] = r;
}

// ---------- LayerNorm(+ELU) D=64, in place ----------
__global__ __launch_bounds__(256) void ln_elu_64(float* __restrict__ x,
                                                 const float* __restrict__ g,
                                                 const float* __restrict__ b) {
  int node = (int)((blockIdx.x * (size_t)blockDim.x + threadIdx.x) >> 6);
  int lane = threadIdx.x & 63;
  if (node >= NN) return;
  float v = x[(size_t)node * 64 + lane];
  float s = v;
#pragma unroll
  for (int o = 1; o < 64; o <<= 1) s += __shfl_xor(s, o);
  float mean = s * (1.f / 64.f);
  float dv = v - mean;
  float q = dv * dv;
#pragma unroll
  for (int o = 1; o < 64; o <<= 1) q += __shfl_xor(q, o);
  float rstd = rsqrtf(q * (1.f / 64.f) + 1e-5f);
  x[(size_t)node * 64 + lane] = eluf(dv * rstd * g[lane] + b[lane]);
}

// ---------- layer3 epilogue: mean over heads then LN over 32 dims ----------
__global__ __launch_bounds__(256) void ln3_kernel(const float* __restrict__ agg,
                                                  const float* __restrict__ g,
                                                  const float* __restrict__ b,
                                                  float* __restrict__ out) {
  int wv = (int)((blockIdx.x * (size_t)blockDim.x + threadIdx.x) >> 6);
  int lane = threadIdx.x & 63;
  int node = wv * 2 + (lane >> 5);
  int c = lane & 31;
  if (node >= NN) return;
  float y = 0.5f * (agg[(size_t)node * 64 + c] + agg[(size_t)node * 64 + 32 + c]);
  float s = y;
#pragma unroll
  for (int o = 1; o < 32; o <<= 1) s += __shfl_xor(s, o);
  float mean = s * (1.f / 32.f);
  float dy = y - mean;
  float q = dy * dy;
#pragma unroll
  for (int o = 1; o < 32; o <<= 1) q += __shfl_xor(q, o);
  float rstd = rsqrtf(q * (1.f / 32.f) + 1e-5f);
  out[(size_t)node * 32 + c] = dy * rstd * g[c] + b[c];
}

extern "C" void kernel_launch(void* const* d_in, const int* in_sizes, int n_in,
                              void* d_out, int out_size, void* d_ws, size_t ws_size,
                              hipStream_t stream) {
  const float* x    = (const float*)d_in[0];
  const int*   ei   = (const int*)d_in[1];
  const float* W1   = (const float*)d_in[2];
  const float* Wh1a = (const float*)d_in[3];
  const float* bh1a = (const float*)d_in[4];
  const float* Wh2a = (const float*)d_in[5];
  const float* bh2a = (const float*)d_in[6];
  const float* g1   = (const float*)d_in[7];
  const float* b1   = (const float*)d_in[8];
  const float* W2   = (const float*)d_in[9];
  const float* Wh1b = (const float*)d_in[10];
  const float* bh1b = (const float*)d_in[11];
  const float* Wh2b = (const float*)d_in[12];
  const float* bh2b = (const float*)d_in[13];
  const float* g2   = (const float*)d_in[14];
  const float* b2   = (const float*)d_in[15];
  const float* W3   = (const float*)d_in[16];
  const float* Wh1c = (const float*)d_in[17];
  const float* bh1c = (const float*)d_in[18];
  const float* Wh2c = (const float*)d_in[19];
  const float* bh2c = (const float*)d_in[20];
  const float* g3   = (const float*)d_in[21];
  const float* b3   = (const float*)d_in[22];

  float* out  = (float*)d_out;
  float* o_x3 = out;                           // N*32
  float* o_h1 = out + (size_t)NN * 32;         // N*64
  float* o_h2 = o_h1 + (size_t)NN * 64;        // N*64
  float* o_h3 = o_h2 + (size_t)NN * 64;        // N*64
  float* o_al = o_h3 + (size_t)NN * 64;        // EPN*2 (logits then alpha)

  float* ws  = (float*)d_ws;
  float* A   = ws;                             // N*256 (xt buffer)
  float* Bb  = ws + (size_t)NN * 256;          // N*256 (agg / x buffer)
  int* cnt    = (int*)(Bb + (size_t)NN * 256); // NN
  int* rowptr = cnt + NN;                      // NN+1
  int* fill   = rowptr + NN + 1;               // NN
  int* eids   = fill + NN;                     // EPN
  float* mbuf = (float*)(eids + EPN);          // NN*2
  float* sbuf = mbuf + (size_t)NN * 2;         // NN*2

  dim3 blk(256);
  int gEdges = (EPN + 255) / 256;
  int gNodeW = (NN * 64 + 255) / 256;
  int gLn3 = ((NN / 2) * 64) / 256;
  int gRows = (NN + 63) / 64;
  int gPairs = (int)(((size_t)EPN * 2 + 255) / 256);
  int gAux = (2 * NN + 63) / 64;

  // ---------------- CSR by dst (shared by all 3 layers) ----------------
  hipMemsetAsync(cnt, 0, (size_t)NN * 4, stream);
  hist_kernel<<<gEdges, blk, 0, stream>>>(ei, cnt);
  scan_kernel<<<1, 1024, 0, stream>>>(cnt, rowptr, fill);
  scatter_kernel<<<gEdges, blk, 0, stream>>>(ei, fill, eids);

  // ---------------- Layer 1: 512 -> 2x128 (concat) ----------------
  gemm_mfma<8><<<dim3(2, gRows), blk, 0, stream>>>(x, W1, A, NN, 256, 512);
  aux_mfma<128><<<gAux, blk, 0, stream>>>(A, Wh1a, bh1a, Wh2a, bh2a, o_h1, 1.0f);
  gat_online_256<<<gNodeW, blk, 0, stream>>>(A, ei, rowptr, eids, Bb);
  ln_elu_256<<<gNodeW, blk, 0, stream>>>(Bb, g1, b1);

  // ---------------- Layer 2: 256 -> 2x32 (concat) ----------------
  gemm_mfma<4><<<dim3(1, gRows), blk, 0, stream>>>(Bb, W2, A, NN, 64, 256);
  aux_mfma<32><<<gAux, blk, 0, stream>>>(A, Wh1b, bh1b, Wh2b, bh2b, o_h2, 0.5f);
  gat_online_64<<<gNodeW, blk, 0, stream>>>(A, ei, rowptr, eids, Bb, nullptr, nullptr, nullptr);
  ln_elu_64<<<gNodeW, blk, 0, stream>>>(Bb, g2, b2);

  // ---------------- Layer 3: 64 -> 2x32 (mean) ----------------
  gemm_mfma<4><<<dim3(1, gRows), blk, 0, stream>>>(Bb, W3, A, NN, 64, 64);
  aux_mfma<32><<<gAux, blk, 0, stream>>>(A, Wh1c, bh1c, Wh2c, bh2c, o_h3, 1.0f);
  gat_online_64<<<gNodeW, blk, 0, stream>>>(A, ei, rowptr, eids, Bb, o_al, mbuf, sbuf);
  alpha_fix<<<gPairs, blk, 0, stream>>>(o_al, ei, mbuf, sbuf);
  ln3_kernel<<<gLn3, blk, 0, stream>>>(Bb, g3, b3, o_x3);
}

// Round 5
// 705.111 us; speedup vs baseline: 6.3288x; 1.2842x over previous
//
#include <hip/hip_runtime.h>

#define NN 50000
#define EE 800000
#define EPN 850000   // EE + NN (self loops appended)

typedef __attribute__((ext_vector_type(8))) short bf16x8;
typedef __attribute__((ext_vector_type(4))) float f32x4;
typedef unsigned short ushort_t;

// ---------- helpers ----------
__device__ __forceinline__ float eluf(float v) { return v > 0.f ? v : expm1f(v); }
__device__ __forceinline__ unsigned short f2bf(float f) {
  unsigned u = __float_as_uint(f);
  unsigned r = (u + 0x7FFFu + ((u >> 16) & 1u)) >> 16;
  return (unsigned short)r;
}
__device__ __forceinline__ float bf2f(unsigned short b) {
  return __uint_as_float(((unsigned)b) << 16);
}

// ---------- W1 pre-convert: W[512,256] f32 -> hi/lo bf16 in [col][k] ----------
__global__ __launch_bounds__(256) void conv_w1(const float* __restrict__ W,
                                               ushort_t* __restrict__ Wh,
                                               ushort_t* __restrict__ Wl) {
  int idx = blockIdx.x * 256 + threadIdx.x;  // over 256*512, idx = n*512 + k
  if (idx >= 256 * 512) return;
  int n = idx >> 9, k = idx & 511;
  float v = W[(size_t)k * 256 + n];
  unsigned short h = f2bf(v);
  Wh[idx] = h;
  Wl[idx] = f2bf(v - bf2f(h));
}

// ---------- layer-1 GEMM: C[M,256] = A[M,512] @ W1, bf16x3, B preconverted ----------
__global__ __launch_bounds__(256) void gemm1_mfma(const float* __restrict__ A,
                                                  const ushort_t* __restrict__ BhG,
                                                  const ushort_t* __restrict__ BlG,
                                                  float* __restrict__ C, int M) {
  constexpr int K = 512;
  __shared__ ushort_t Bh[256 * 40], Bl[256 * 40];
  int tid = threadIdx.x;
  int w = tid >> 6, lane = tid & 63, l15 = lane & 15, l4 = lane >> 4;
  int row0 = blockIdx.x * 64;
  int arow = row0 + w * 16 + l15;
  int arowc = arow < M ? arow : M - 1;

  f32x4 acc[16];
#pragma unroll
  for (int t = 0; t < 16; ++t) acc[t] = (f32x4){0.f, 0.f, 0.f, 0.f};

  for (int k0 = 0; k0 < K; k0 += 32) {
    // issue A loads first (overlap with B staging)
    float4 p0 = *(const float4*)&A[(size_t)arowc * K + k0 + l4 * 8];
    float4 p1 = *(const float4*)&A[(size_t)arowc * K + k0 + l4 * 8 + 4];
    // stage B: thread owns col=tid, copies 32 k-values (64B) per buffer
    {
      const ushort_t* sh = BhG + (size_t)tid * K + k0;
      const ushort_t* sl = BlG + (size_t)tid * K + k0;
      ushort_t* dh = &Bh[tid * 40];
      ushort_t* dl = &Bl[tid * 40];
      *(bf16x8*)(dh) = *(const bf16x8*)(sh);
      *(bf16x8*)(dh + 8) = *(const bf16x8*)(sh + 8);
      *(bf16x8*)(dh + 16) = *(const bf16x8*)(sh + 16);
      *(bf16x8*)(dh + 24) = *(const bf16x8*)(sh + 24);
      *(bf16x8*)(dl) = *(const bf16x8*)(sl);
      *(bf16x8*)(dl + 8) = *(const bf16x8*)(sl + 8);
      *(bf16x8*)(dl + 16) = *(const bf16x8*)(sl + 16);
      *(bf16x8*)(dl + 24) = *(const bf16x8*)(sl + 24);
    }
    __syncthreads();
    // convert A slice to hi/lo fragments in regs
    bf16x8 ah, al;
    {
      float v[8] = {p0.x, p0.y, p0.z, p0.w, p1.x, p1.y, p1.z, p1.w};
#pragma unroll
      for (int i = 0; i < 8; ++i) {
        unsigned short h = f2bf(v[i]);
        ah[i] = (short)h;
        al[i] = (short)f2bf(v[i] - bf2f(h));
      }
    }
#pragma unroll
    for (int t = 0; t < 16; ++t) {
      bf16x8 b_h = *(const bf16x8*)&Bh[(t * 16 + l15) * 40 + l4 * 8];
      bf16x8 b_l = *(const bf16x8*)&Bl[(t * 16 + l15) * 40 + l4 * 8];
      acc[t] = __builtin_amdgcn_mfma_f32_16x16x32_bf16(ah, b_h, acc[t], 0, 0, 0);
      acc[t] = __builtin_amdgcn_mfma_f32_16x16x32_bf16(ah, b_l, acc[t], 0, 0, 0);
      acc[t] = __builtin_amdgcn_mfma_f32_16x16x32_bf16(al, b_h, acc[t], 0, 0, 0);
    }
    __syncthreads();
  }
#pragma unroll
  for (int t = 0; t < 16; ++t) {
#pragma unroll
    for (int r = 0; r < 4; ++r) {
      int grow = row0 + w * 16 + l4 * 4 + r;
      if (grow < M) C[(size_t)grow * 256 + t * 16 + l15] = acc[t][r];
    }
  }
}

// ---------- MFMA bf16x3 GEMM (layers 2,3): C[M,N]=A[M,K]@B[K,N] ----------
template <int NT>
__global__ __launch_bounds__(256) void gemm_mfma(const float* __restrict__ A,
                                                 const float* __restrict__ B,
                                                 float* __restrict__ C,
                                                 int M, int N, int K) {
  __shared__ unsigned short Ah[64 * 40], Al[64 * 40];
  __shared__ unsigned short Bh[NT * 16 * 40], Bl[NT * 16 * 40];
  int tid = threadIdx.x;
  int wave = tid >> 6, lane = tid & 63;
  int l15 = lane & 15, l4 = lane >> 4;
  int row0 = blockIdx.y * 64, col0 = blockIdx.x * (NT * 16);

  f32x4 acc[NT];
#pragma unroll
  for (int t = 0; t < NT; ++t) acc[t] = (f32x4){0.f, 0.f, 0.f, 0.f};

  int ar = tid >> 2;
  int ak = (tid & 3) * 8;
  constexpr int TPC = 256 / (NT * 16);
  constexpr int NK = 32 / TPC;
  int bc = tid / TPC;
  int bk = (tid % TPC) * NK;

  for (int k0 = 0; k0 < K; k0 += 32) {
    {
      float v[8];
      int grow = row0 + ar;
      if (grow < M) {
        float4 q0 = *(const float4*)&A[(size_t)grow * K + k0 + ak];
        float4 q1 = *(const float4*)&A[(size_t)grow * K + k0 + ak + 4];
        v[0] = q0.x; v[1] = q0.y; v[2] = q0.z; v[3] = q0.w;
        v[4] = q1.x; v[5] = q1.y; v[6] = q1.z; v[7] = q1.w;
      } else {
#pragma unroll
        for (int i = 0; i < 8; ++i) v[i] = 0.f;
      }
      bf16x8 hv, lv;
#pragma unroll
      for (int i = 0; i < 8; ++i) {
        unsigned short h = f2bf(v[i]);
        hv[i] = (short)h;
        lv[i] = (short)f2bf(v[i] - bf2f(h));
      }
      *(bf16x8*)&Ah[ar * 40 + ak] = hv;
      *(bf16x8*)&Al[ar * 40 + ak] = lv;
    }
    {
#pragma unroll
      for (int i = 0; i < NK; ++i) {
        float v = B[(size_t)(k0 + bk + i) * N + col0 + bc];
        unsigned short h = f2bf(v);
        Bh[bc * 40 + bk + i] = h;
        Bl[bc * 40 + bk + i] = f2bf(v - bf2f(h));
      }
    }
    __syncthreads();
    bf16x8 a_h = *(const bf16x8*)&Ah[(wave * 16 + l15) * 40 + l4 * 8];
    bf16x8 a_l = *(const bf16x8*)&Al[(wave * 16 + l15) * 40 + l4 * 8];
#pragma unroll
    for (int t = 0; t < NT; ++t) {
      bf16x8 b_h = *(const bf16x8*)&Bh[(t * 16 + l15) * 40 + l4 * 8];
      bf16x8 b_l = *(const bf16x8*)&Bl[(t * 16 + l15) * 40 + l4 * 8];
      acc[t] = __builtin_amdgcn_mfma_f32_16x16x32_bf16(a_h, b_h, acc[t], 0, 0, 0);
      acc[t] = __builtin_amdgcn_mfma_f32_16x16x32_bf16(a_h, b_l, acc[t], 0, 0, 0);
      acc[t] = __builtin_amdgcn_mfma_f32_16x16x32_bf16(a_l, b_h, acc[t], 0, 0, 0);
    }
    __syncthreads();
  }
#pragma unroll
  for (int t = 0; t < NT; ++t) {
#pragma unroll
    for (int r = 0; r < 4; ++r) {
      int grow = row0 + wave * 16 + l4 * 4 + r;
      if (grow < M) C[(size_t)grow * N + col0 + t * 16 + l15] = acc[t][r];
    }
  }
}

// ---------- fused aux head via MFMA ----------
template <int C>
__global__ __launch_bounds__(256) void aux_mfma(const float* __restrict__ xt,
                                                const float* __restrict__ Wh1,
                                                const float* __restrict__ bh1,
                                                const float* __restrict__ Wh2,
                                                const float* __restrict__ bh2,
                                                float* __restrict__ hout,
                                                float scale) {
  constexpr int KS = C / 32;
  constexpr int LDB = C + 8;
  __shared__ unsigned short BhS[64 * LDB], BlS[64 * LDB];
  __shared__ float w2s[64 * 32];
  __shared__ float hid[64 * 68];
  int tid = threadIdx.x;
  for (int i = tid; i < C * 64; i += 256) {
    int k = i >> 6, col = i & 63;
    float v = Wh1[i];
    unsigned short h = f2bf(v);
    BhS[col * LDB + k] = h;
    BlS[col * LDB + k] = f2bf(v - bf2f(h));
  }
  for (int i = tid; i < 64 * 32; i += 256) w2s[i] = Wh2[i];
  __syncthreads();

  int w = tid >> 6, lane = tid & 63, l15 = lane & 15, l4 = lane >> 4;
  int gr = blockIdx.x * 64 + w * 16 + l15;
  const int M2 = 2 * NN;

  f32x4 acc[4];
#pragma unroll
  for (int t = 0; t < 4; ++t) acc[t] = (f32x4){0.f, 0.f, 0.f, 0.f};

#pragma unroll
  for (int ks = 0; ks < KS; ++ks) {
    bf16x8 ah, al;
    if (gr < M2) {
      const float* p = xt + (size_t)gr * C + ks * 32 + l4 * 8;
      float4 p0 = *(const float4*)p;
      float4 p1 = *(const float4*)(p + 4);
      float v[8] = {p0.x, p0.y, p0.z, p0.w, p1.x, p1.y, p1.z, p1.w};
#pragma unroll
      for (int i = 0; i < 8; ++i) {
        unsigned short h = f2bf(v[i]);
        ah[i] = (short)h;
        al[i] = (short)f2bf(v[i] - bf2f(h));
      }
    } else {
      ah = (bf16x8){0, 0, 0, 0, 0, 0, 0, 0};
      al = ah;
    }
#pragma unroll
    for (int t = 0; t < 4; ++t) {
      bf16x8 b_h = *(const bf16x8*)&BhS[(t * 16 + l15) * LDB + ks * 32 + l4 * 8];
      bf16x8 b_l = *(const bf16x8*)&BlS[(t * 16 + l15) * LDB + ks * 32 + l4 * 8];
      acc[t] = __builtin_amdgcn_mfma_f32_16x16x32_bf16(ah, b_h, acc[t], 0, 0, 0);
      acc[t] = __builtin_amdgcn_mfma_f32_16x16x32_bf16(ah, b_l, acc[t], 0, 0, 0);
      acc[t] = __builtin_amdgcn_mfma_f32_16x16x32_bf16(al, b_h, acc[t], 0, 0, 0);
    }
  }
#pragma unroll
  for (int t = 0; t < 4; ++t) {
    float bb = bh1[t * 16 + l15];
#pragma unroll
    for (int r = 0; r < 4; ++r)
      hid[(w * 16 + l4 * 4 + r) * 68 + t * 16 + l15] = eluf(acc[t][r] + bb);
  }
  __syncthreads();
  float4 o0 = make_float4(0.f, 0.f, 0.f, 0.f), o1 = o0;
  const float* hrow = &hid[(w * 16 + l15) * 68];
#pragma unroll 8
  for (int k = 0; k < 64; ++k) {
    float hv = hrow[k];
    float4 wa = *(const float4*)&w2s[k * 32 + l4 * 8];
    float4 wb = *(const float4*)&w2s[k * 32 + l4 * 8 + 4];
    o0.x += hv * wa.x; o0.y += hv * wa.y; o0.z += hv * wa.z; o0.w += hv * wa.w;
    o1.x += hv * wb.x; o1.y += hv * wb.y; o1.z += hv * wb.z; o1.w += hv * wb.w;
  }
  if (gr < M2) {
    float4 ba = *(const float4*)&bh2[l4 * 8];
    float4 bb = *(const float4*)&bh2[l4 * 8 + 4];
    o0.x = (o0.x + ba.x) * scale; o0.y = (o0.y + ba.y) * scale;
    o0.z = (o0.z + ba.z) * scale; o0.w = (o0.w + ba.w) * scale;
    o1.x = (o1.x + bb.x) * scale; o1.y = (o1.y + bb.y) * scale;
    o1.z = (o1.z + bb.z) * scale; o1.w = (o1.w + bb.w) * scale;
    float* dst = hout + (size_t)(gr >> 1) * 64 + (gr & 1) * 32 + l4 * 8;
    *(float4*)dst = o0;
    *(float4*)(dst + 4) = o1;
  }
}

// ---------- CSR build ----------
__global__ __launch_bounds__(256) void hist_kernel(const int* __restrict__ ei,
                                                   int* __restrict__ cnt) {
  int e = blockIdx.x * 256 + threadIdx.x;
  if (e >= EPN) return;
  int d = (e < EE) ? ei[EE + e] : e - EE;
  atomicAdd(&cnt[d], 1);
}

__global__ __launch_bounds__(1024) void scan_blocks(const int* __restrict__ cnt,
                                                    int* __restrict__ tmp,
                                                    int* __restrict__ bsum) {
  __shared__ int lds[1024];
  int t = threadIdx.x, idx = blockIdx.x * 1024 + t;
  int v = (idx < NN) ? cnt[idx] : 0;
  lds[t] = v;
  __syncthreads();
  for (int off = 1; off < 1024; off <<= 1) {
    int add = (t >= off) ? lds[t - off] : 0;
    __syncthreads();
    lds[t] += add;
    __syncthreads();
  }
  if (idx < NN) tmp[idx] = lds[t];
  if (t == 1023) bsum[blockIdx.x] = lds[t];
}

__global__ __launch_bounds__(64) void scan_bsum(int* __restrict__ bsum, int nb) {
  int t = threadIdx.x;
  int v = (t < nb) ? bsum[t] : 0;
#pragma unroll
  for (int off = 1; off < 64; off <<= 1) {
    int u = __shfl_up(v, off);
    if (t >= off) v += u;
  }
  if (t < nb) bsum[t] = v;
}

__global__ __launch_bounds__(256) void scan_final(const int* __restrict__ cnt,
                                                  const int* __restrict__ tmp,
                                                  const int* __restrict__ bsum,
                                                  int* __restrict__ rowptr,
                                                  int* __restrict__ fill) {
  int idx = blockIdx.x * 256 + threadIdx.x;
  if (idx >= NN) return;
  int b = idx >> 10;
  int off = (b > 0) ? bsum[b - 1] : 0;
  int inc = tmp[idx] + off;
  rowptr[idx + 1] = inc;
  fill[idx] = inc - cnt[idx];
  if (idx == 0) rowptr[0] = 0;
}

__global__ __launch_bounds__(256) void scatter_kernel(const int* __restrict__ ei,
                                                      int* __restrict__ fill,
                                                      int* __restrict__ eids,
                                                      int* __restrict__ srcs) {
  int e = blockIdx.x * 256 + threadIdx.x;
  if (e >= EPN) return;
  int d, s;
  if (e < EE) { d = ei[EE + e]; s = ei[e]; } else { d = s = e - EE; }
  int pos = atomicAdd(&fill[d], 1);
  eids[pos] = e;
  srcs[pos] = s;
}

// ---------- ONLINE single-pass GAT, D=256, chunk-4 pipelined ----------
#define STEP256(av)                                                        \
  {                                                                        \
    float p = av.x * dstv.x + av.y * dstv.y + av.z * dstv.z + av.w * dstv.w; \
    p += __shfl_xor(p, 1); p += __shfl_xor(p, 2); p += __shfl_xor(p, 4);   \
    p += __shfl_xor(p, 8); p += __shfl_xor(p, 16);                         \
    p *= 0.08838834764831843f;                                             \
    float mn = fmaxf(m, p);                                                \
    float sc = expf(m - mn), w = expf(p - mn);                             \
    s = s * sc + w;                                                        \
    acc.x = acc.x * sc + w * av.x; acc.y = acc.y * sc + w * av.y;          \
    acc.z = acc.z * sc + w * av.z; acc.w = acc.w * sc + w * av.w;          \
    m = mn;                                                                \
  }

__global__ __launch_bounds__(256) void gat_online_256(const float* __restrict__ xt,
                                                      const int* __restrict__ srcs,
                                                      const int* __restrict__ rowptr,
                                                      float* __restrict__ outb) {
  int node = (int)((blockIdx.x * (size_t)blockDim.x + threadIdx.x) >> 6);
  int lane = threadIdx.x & 63;
  if (node >= NN) return;
  int start = rowptr[node], end = rowptr[node + 1];
  float4 dstv = ((const float4*)(xt + (size_t)node * 256))[lane];
  float m = -1e30f, s = 0.f;
  float4 acc = make_float4(0.f, 0.f, 0.f, 0.f);
  int i = start;
  for (; i + 4 <= end; i += 4) {
    int s0 = srcs[i], s1 = srcs[i + 1], s2 = srcs[i + 2], s3 = srcs[i + 3];
    float4 a0 = ((const float4*)(xt + (size_t)s0 * 256))[lane];
    float4 a1 = ((const float4*)(xt + (size_t)s1 * 256))[lane];
    float4 a2 = ((const float4*)(xt + (size_t)s2 * 256))[lane];
    float4 a3 = ((const float4*)(xt + (size_t)s3 * 256))[lane];
    STEP256(a0); STEP256(a1); STEP256(a2); STEP256(a3);
  }
  for (; i < end; ++i) {
    int s0 = srcs[i];
    float4 a0 = ((const float4*)(xt + (size_t)s0 * 256))[lane];
    STEP256(a0);
  }
  float inv = 1.f / (s + 1e-16f);
  acc.x *= inv; acc.y *= inv; acc.z *= inv; acc.w *= inv;
  ((float4*)(outb + (size_t)node * 256))[lane] = acc;
}

// ---------- ONLINE single-pass GAT, D=64, chunk-8 pipelined ----------
#define STEP64(av)                                                 \
  {                                                                \
    float p = av * dv;                                             \
    p += __shfl_xor(p, 1); p += __shfl_xor(p, 2);                  \
    p += __shfl_xor(p, 4); p += __shfl_xor(p, 8);                  \
    p += __shfl_xor(p, 16);                                        \
    p *= 0.17677669529663687f;                                     \
    float mn = fmaxf(m, p);                                        \
    float sc = expf(m - mn), w = expf(p - mn);                     \
    s = s * sc + w;                                                \
    acc = acc * sc + w * av;                                       \
    m = mn;                                                        \
  }

__global__ __launch_bounds__(256) void gat_online_64(const float* __restrict__ xt,
                                                     const int* __restrict__ srcs,
                                                     const int* __restrict__ rowptr,
                                                     float* __restrict__ outb) {
  int node = (int)((blockIdx.x * (size_t)blockDim.x + threadIdx.x) >> 6);
  int lane = threadIdx.x & 63;
  if (node >= NN) return;
  int start = rowptr[node], end = rowptr[node + 1];
  float dv = xt[(size_t)node * 64 + lane];
  float m = -1e30f, s = 0.f, acc = 0.f;
  int i = start;
  for (; i + 8 <= end; i += 8) {
    float aa[8];
#pragma unroll
    for (int j = 0; j < 8; ++j) {
      int sj = srcs[i + j];
      aa[j] = xt[(size_t)sj * 64 + lane];
    }
#pragma unroll
    for (int j = 0; j < 8; ++j) STEP64(aa[j]);
  }
  for (; i < end; ++i) {
    int sj = srcs[i];
    float a0 = xt[(size_t)sj * 64 + lane];
    STEP64(a0);
  }
  float inv = 1.f / (s + 1e-16f);
  outb[(size_t)node * 64 + lane] = acc * inv;
}

// D=64 variant that also records logits + (m,s) for the alpha output (layer 3)
__global__ __launch_bounds__(256) void gat_online_64a(const float* __restrict__ xt,
                                                      const int* __restrict__ srcs,
                                                      const int* __restrict__ eids,
                                                      const int* __restrict__ rowptr,
                                                      float* __restrict__ outb,
                                                      float* __restrict__ logit_out,
                                                      float* __restrict__ mbuf,
                                                      float* __restrict__ sbuf) {
  int node = (int)((blockIdx.x * (size_t)blockDim.x + threadIdx.x) >> 6);
  int lane = threadIdx.x & 63;
  if (node >= NN) return;
  int half = lane >> 5, l32 = lane & 31;
  int start = rowptr[node], end = rowptr[node + 1];
  float dv = xt[(size_t)node * 64 + lane];
  float m = -1e30f, s = 0.f, acc = 0.f;
  for (int i = start; i < end; ++i) {
    int sj = srcs[i];
    int e = eids[i];
    float a = xt[(size_t)sj * 64 + lane];
    float p = a * dv;
    p += __shfl_xor(p, 1); p += __shfl_xor(p, 2);
    p += __shfl_xor(p, 4); p += __shfl_xor(p, 8);
    p += __shfl_xor(p, 16);
    p *= 0.17677669529663687f;
    if (l32 == 0) logit_out[(size_t)e * 2 + half] = p;
    float mn = fmaxf(m, p);
    float sc = expf(m - mn), w = expf(p - mn);
    s = s * sc + w;
    acc = acc * sc + w * a;
    m = mn;
  }
  float inv = 1.f / (s + 1e-16f);
  outb[(size_t)node * 64 + lane] = acc * inv;
  if (l32 == 0) {
    mbuf[(size_t)node * 2 + half] = m;
    sbuf[(size_t)node * 2 + half] = s;
  }
}

// ---------- alpha fix-up ----------
__global__ __launch_bounds__(256) void alpha_fix(float* __restrict__ al,
                                                 const int* __restrict__ ei,
                                                 const float* __restrict__ mbuf,
                                                 const float* __restrict__ sbuf) {
  size_t i = blockIdx.x * (size_t)blockDim.x + threadIdx.x;
  if (i >= (size_t)EPN * 2) return;
  int e = (int)(i >> 1), h = (int)(i & 1);
  int d = (e < EE) ? ei[EE + e] : e - EE;
  al[i] = expf(al[i] - mbuf[(size_t)d * 2 + h]) / (sbuf[(size_t)d * 2 + h] + 1e-16f);
}

// ---------- LayerNorm(+ELU) D=256, in place ----------
__global__ __launch_bounds__(256) void ln_elu_256(float* __restrict__ x,
                                                  const float* __restrict__ g,
                                                  const float* __restrict__ b) {
  int node = (int)((blockIdx.x * (size_t)blockDim.x + threadIdx.x) >> 6);
  int lane = threadIdx.x & 63;
  if (node >= NN) return;
  float4* row = (float4*)(x + (size_t)node * 256);
  float4 v = row[lane];
  float s = v.x + v.y + v.z + v.w;
#pragma unroll
  for (int o = 1; o < 64; o <<= 1) s += __shfl_xor(s, o);
  float mean = s * (1.f / 256.f);
  float dx = v.x - mean, dy = v.y - mean, dz = v.z - mean, dw = v.w - mean;
  float q = dx * dx + dy * dy + dz * dz + dw * dw;
#pragma unroll
  for (int o = 1; o < 64; o <<= 1) q += __shfl_xor(q, o);
  float rstd = rsqrtf(q * (1.f / 256.f) + 1e-5f);
  float4 gg = ((const float4*)g)[lane], bb = ((const float4*)b)[lane];
  float4 r;
  r.x = eluf(dx * rstd * gg.x + bb.x);
  r.y = eluf(dy * rstd * gg.y + bb.y);
  r.z = eluf(dz * rstd * gg.z + bb.z);
  r.w = eluf(dw * rstd * gg.w + bb.w);
  row[lane] = r;
}

// ---------- LayerNorm(+ELU) D=64, in place ----------
__global__ __launch_bounds__(256) void ln_elu_64(float* __restrict__ x,
                                                 const float* __restrict__ g,
                                                 const float* __restrict__ b) {
  int node = (int)((blockIdx.x * (size_t)blockDim.x + threadIdx.x) >> 6);
  int lane = threadIdx.x & 63;
  if (node >= NN) return;
  float v = x[(size_t)node * 64 + lane];
  float s = v;
#pragma unroll
  for (int o = 1; o < 64; o <<= 1) s += __shfl_xor(s, o);
  float mean = s * (1.f / 64.f);
  float dv = v - mean;
  float q = dv * dv;
#pragma unroll
  for (int o = 1; o < 64; o <<= 1) q += __shfl_xor(q, o);
  float rstd = rsqrtf(q * (1.f / 64.f) + 1e-5f);
  x[(size_t)node * 64 + lane] = eluf(dv * rstd * g[lane] + b[lane]);
}

// ---------- layer3 epilogue ----------
__global__ __launch_bounds__(256) void ln3_kernel(const float* __restrict__ agg,
                                                  const float* __restrict__ g,
                                                  const float* __restrict__ b,
                                                  float* __restrict__ out) {
  int wv = (int)((blockIdx.x * (size_t)blockDim.x + threadIdx.x) >> 6);
  int lane = threadIdx.x & 63;
  int node = wv * 2 + (lane >> 5);
  int c = lane & 31;
  if (node >= NN) return;
  float y = 0.5f * (agg[(size_t)node * 64 + c] + agg[(size_t)node * 64 + 32 + c]);
  float s = y;
#pragma unroll
  for (int o = 1; o < 32; o <<= 1) s += __shfl_xor(s, o);
  float mean = s * (1.f / 32.f);
  float dy = y - mean;
  float q = dy * dy;
#pragma unroll
  for (int o = 1; o < 32; o <<= 1) q += __shfl_xor(q, o);
  float rstd = rsqrtf(q * (1.f / 32.f) + 1e-5f);
  out[(size_t)node * 32 + c] = dy * rstd * g[c] + b[c];
}

extern "C" void kernel_launch(void* const* d_in, const int* in_sizes, int n_in,
                              void* d_out, int out_size, void* d_ws, size_t ws_size,
                              hipStream_t stream) {
  const float* x    = (const float*)d_in[0];
  const int*   ei   = (const int*)d_in[1];
  const float* W1   = (const float*)d_in[2];
  const float* Wh1a = (const float*)d_in[3];
  const float* bh1a = (const float*)d_in[4];
  const float* Wh2a = (const float*)d_in[5];
  const float* bh2a = (const float*)d_in[6];
  const float* g1   = (const float*)d_in[7];
  const float* b1   = (const float*)d_in[8];
  const float* W2   = (const float*)d_in[9];
  const float* Wh1b = (const float*)d_in[10];
  const float* bh1b = (const float*)d_in[11];
  const float* Wh2b = (const float*)d_in[12];
  const float* bh2b = (const float*)d_in[13];
  const float* g2   = (const float*)d_in[14];
  const float* b2   = (const float*)d_in[15];
  const float* W3   = (const float*)d_in[16];
  const float* Wh1c = (const float*)d_in[17];
  const float* bh1c = (const float*)d_in[18];
  const float* Wh2c = (const float*)d_in[19];
  const float* bh2c = (const float*)d_in[20];
  const float* g3   = (const float*)d_in[21];
  const float* b3   = (const float*)d_in[22];

  float* out  = (float*)d_out;
  float* o_x3 = out;                           // N*32
  float* o_h1 = out + (size_t)NN * 32;         // N*64
  float* o_h2 = o_h1 + (size_t)NN * 64;        // N*64
  float* o_h3 = o_h2 + (size_t)NN * 64;        // N*64
  float* o_al = o_h3 + (size_t)NN * 64;        // EPN*2 (logits then alpha)

  float* ws  = (float*)d_ws;
  float* A   = ws;                             // N*256
  float* Bb  = ws + (size_t)NN * 256;          // N*256
  int* cnt    = (int*)(Bb + (size_t)NN * 256); // NN
  int* rowptr = cnt + NN;                      // NN+1
  int* fill   = rowptr + NN + 1;               // NN
  int* eids   = fill + NN;                     // EPN
  int* srcs   = eids + EPN;                    // EPN
  int* tmp    = srcs + EPN;                    // NN
  int* bsum   = tmp + NN;                      // 64
  float* mbuf = (float*)(bsum + 64);           // NN*2
  float* sbuf = mbuf + (size_t)NN * 2;         // NN*2
  ushort_t* W1h = (ushort_t*)(sbuf + (size_t)NN * 2);  // 256*512
  ushort_t* W1l = W1h + 256 * 512;                     // 256*512

  dim3 blk(256);
  int gEdges = (EPN + 255) / 256;
  int gNodeW = (NN * 64 + 255) / 256;
  int gLn3 = ((NN / 2) * 64) / 256;
  int gRows = (NN + 63) / 64;
  int gPairs = (int)(((size_t)EPN * 2 + 255) / 256);
  int gAux = (2 * NN + 63) / 64;
  int nbScan = (NN + 1023) / 1024;

  // ---------------- CSR by dst + W1 preconversion ----------------
  conv_w1<<<512, blk, 0, stream>>>(W1, W1h, W1l);
  hipMemsetAsync(cnt, 0, (size_t)NN * 4, stream);
  hist_kernel<<<gEdges, blk, 0, stream>>>(ei, cnt);
  scan_blocks<<<nbScan, 1024, 0, stream>>>(cnt, tmp, bsum);
  scan_bsum<<<1, 64, 0, stream>>>(bsum, nbScan);
  scan_final<<<(NN + 255) / 256, blk, 0, stream>>>(cnt, tmp, bsum, rowptr, fill);
  scatter_kernel<<<gEdges, blk, 0, stream>>>(ei, fill, eids, srcs);

  // ---------------- Layer 1: 512 -> 2x128 (concat) ----------------
  gemm1_mfma<<<gRows, blk, 0, stream>>>(x, W1h, W1l, A, NN);
  aux_mfma<128><<<gAux, blk, 0, stream>>>(A, Wh1a, bh1a, Wh2a, bh2a, o_h1, 1.0f);
  gat_online_256<<<gNodeW, blk, 0, stream>>>(A, srcs, rowptr, Bb);
  ln_elu_256<<<gNodeW, blk, 0, stream>>>(Bb, g1, b1);

  // ---------------- Layer 2: 256 -> 2x32 (concat) ----------------
  gemm_mfma<4><<<dim3(1, gRows), blk, 0, stream>>>(Bb, W2, A, NN, 64, 256);
  aux_mfma<32><<<gAux, blk, 0, stream>>>(A, Wh1b, bh1b, Wh2b, bh2b, o_h2, 0.5f);
  gat_online_64<<<gNodeW, blk, 0, stream>>>(A, srcs, rowptr, Bb);
  ln_elu_64<<<gNodeW, blk, 0, stream>>>(Bb, g2, b2);

  // ---------------- Layer 3: 64 -> 2x32 (mean) ----------------
  gemm_mfma<4><<<dim3(1, gRows), blk, 0, stream>>>(Bb, W3, A, NN, 64, 64);
  aux_mfma<32><<<gAux, blk, 0, stream>>>(A, Wh1c, bh1c, Wh2c, bh2c, o_h3, 1.0f);
  gat_online_64a<<<gNodeW, blk, 0, stream>>>(A, srcs, eids, rowptr, Bb, o_al, mbuf, sbuf);
  alpha_fix<<<gPairs, blk, 0, stream>>>(o_al, ei, mbuf, sbuf);
  ln3_kernel<<<gLn3, blk, 0, stream>>>(Bb, g3, b3, o_x3);
}

// Round 6
// 661.989 us; speedup vs baseline: 6.7410x; 1.0651x over previous
//
#include <hip/hip_runtime.h>

#define NN 50000
#define EE 800000
#define EPN 850000   // EE + NN (self loops appended)

typedef __attribute__((ext_vector_type(8))) short bf16x8;
typedef __attribute__((ext_vector_type(4))) float f32x4;
typedef unsigned short ushort_t;

// ---------- helpers ----------
__device__ __forceinline__ float eluf(float v) { return v > 0.f ? v : expm1f(v); }
__device__ __forceinline__ float dot4(float4 a, float4 b) {
  return a.x * b.x + a.y * b.y + a.z * b.z + a.w * b.w;
}
__device__ __forceinline__ unsigned short f2bf(float f) {
  unsigned u = __float_as_uint(f);
  unsigned r = (u + 0x7FFFu + ((u >> 16) & 1u)) >> 16;
  return (unsigned short)r;
}
__device__ __forceinline__ float bf2f(unsigned short b) {
  return __uint_as_float(((unsigned)b) << 16);
}

// ---------- W1 pre-convert: W[512,256] f32 -> hi/lo bf16 in [col][k] ----------
__global__ __launch_bounds__(256) void conv_w1(const float* __restrict__ W,
                                               ushort_t* __restrict__ Wh,
                                               ushort_t* __restrict__ Wl) {
  int idx = blockIdx.x * 256 + threadIdx.x;
  if (idx >= 256 * 512) return;
  int n = idx >> 9, k = idx & 511;
  float v = W[(size_t)k * 256 + n];
  unsigned short h = f2bf(v);
  Wh[idx] = h;
  Wl[idx] = f2bf(v - bf2f(h));
}

// ---------- layer-1 GEMM: C[M,256] = A[M,512] @ W1, bf16x3, B preconverted ----------
__global__ __launch_bounds__(256) void gemm1_mfma(const float* __restrict__ A,
                                                  const ushort_t* __restrict__ BhG,
                                                  const ushort_t* __restrict__ BlG,
                                                  float* __restrict__ C, int M) {
  constexpr int K = 512;
  __shared__ ushort_t Bh[256 * 40], Bl[256 * 40];
  int tid = threadIdx.x;
  int w = tid >> 6, lane = tid & 63, l15 = lane & 15, l4 = lane >> 4;
  int row0 = blockIdx.x * 64;
  int arow = row0 + w * 16 + l15;
  int arowc = arow < M ? arow : M - 1;

  f32x4 acc[16];
#pragma unroll
  for (int t = 0; t < 16; ++t) acc[t] = (f32x4){0.f, 0.f, 0.f, 0.f};

  for (int k0 = 0; k0 < K; k0 += 32) {
    float4 p0 = *(const float4*)&A[(size_t)arowc * K + k0 + l4 * 8];
    float4 p1 = *(const float4*)&A[(size_t)arowc * K + k0 + l4 * 8 + 4];
    {
      const ushort_t* sh = BhG + (size_t)tid * K + k0;
      const ushort_t* sl = BlG + (size_t)tid * K + k0;
      ushort_t* dh = &Bh[tid * 40];
      ushort_t* dl = &Bl[tid * 40];
      *(bf16x8*)(dh) = *(const bf16x8*)(sh);
      *(bf16x8*)(dh + 8) = *(const bf16x8*)(sh + 8);
      *(bf16x8*)(dh + 16) = *(const bf16x8*)(sh + 16);
      *(bf16x8*)(dh + 24) = *(const bf16x8*)(sh + 24);
      *(bf16x8*)(dl) = *(const bf16x8*)(sl);
      *(bf16x8*)(dl + 8) = *(const bf16x8*)(sl + 8);
      *(bf16x8*)(dl + 16) = *(const bf16x8*)(sl + 16);
      *(bf16x8*)(dl + 24) = *(const bf16x8*)(sl + 24);
    }
    __syncthreads();
    bf16x8 ah, al;
    {
      float v[8] = {p0.x, p0.y, p0.z, p0.w, p1.x, p1.y, p1.z, p1.w};
#pragma unroll
      for (int i = 0; i < 8; ++i) {
        unsigned short h = f2bf(v[i]);
        ah[i] = (short)h;
        al[i] = (short)f2bf(v[i] - bf2f(h));
      }
    }
#pragma unroll
    for (int t = 0; t < 16; ++t) {
      bf16x8 b_h = *(const bf16x8*)&Bh[(t * 16 + l15) * 40 + l4 * 8];
      bf16x8 b_l = *(const bf16x8*)&Bl[(t * 16 + l15) * 40 + l4 * 8];
      acc[t] = __builtin_amdgcn_mfma_f32_16x16x32_bf16(ah, b_h, acc[t], 0, 0, 0);
      acc[t] = __builtin_amdgcn_mfma_f32_16x16x32_bf16(ah, b_l, acc[t], 0, 0, 0);
      acc[t] = __builtin_amdgcn_mfma_f32_16x16x32_bf16(al, b_h, acc[t], 0, 0, 0);
    }
    __syncthreads();
  }
#pragma unroll
  for (int t = 0; t < 16; ++t) {
#pragma unroll
    for (int r = 0; r < 4; ++r) {
      int grow = row0 + w * 16 + l4 * 4 + r;
      if (grow < M) C[(size_t)grow * 256 + t * 16 + l15] = acc[t][r];
    }
  }
}

// ---------- MFMA bf16x3 GEMM (layers 2,3): C[M,N]=A[M,K]@B[K,N] ----------
template <int NT>
__global__ __launch_bounds__(256) void gemm_mfma(const float* __restrict__ A,
                                                 const float* __restrict__ B,
                                                 float* __restrict__ C,
                                                 int M, int N, int K) {
  __shared__ unsigned short Ah[64 * 40], Al[64 * 40];
  __shared__ unsigned short Bh[NT * 16 * 40], Bl[NT * 16 * 40];
  int tid = threadIdx.x;
  int wave = tid >> 6, lane = tid & 63;
  int l15 = lane & 15, l4 = lane >> 4;
  int row0 = blockIdx.y * 64, col0 = blockIdx.x * (NT * 16);

  f32x4 acc[NT];
#pragma unroll
  for (int t = 0; t < NT; ++t) acc[t] = (f32x4){0.f, 0.f, 0.f, 0.f};

  int ar = tid >> 2;
  int ak = (tid & 3) * 8;
  constexpr int TPC = 256 / (NT * 16);
  constexpr int NK = 32 / TPC;
  int bc = tid / TPC;
  int bk = (tid % TPC) * NK;

  for (int k0 = 0; k0 < K; k0 += 32) {
    {
      float v[8];
      int grow = row0 + ar;
      if (grow < M) {
        float4 q0 = *(const float4*)&A[(size_t)grow * K + k0 + ak];
        float4 q1 = *(const float4*)&A[(size_t)grow * K + k0 + ak + 4];
        v[0] = q0.x; v[1] = q0.y; v[2] = q0.z; v[3] = q0.w;
        v[4] = q1.x; v[5] = q1.y; v[6] = q1.z; v[7] = q1.w;
      } else {
#pragma unroll
        for (int i = 0; i < 8; ++i) v[i] = 0.f;
      }
      bf16x8 hv, lv;
#pragma unroll
      for (int i = 0; i < 8; ++i) {
        unsigned short h = f2bf(v[i]);
        hv[i] = (short)h;
        lv[i] = (short)f2bf(v[i] - bf2f(h));
      }
      *(bf16x8*)&Ah[ar * 40 + ak] = hv;
      *(bf16x8*)&Al[ar * 40 + ak] = lv;
    }
    {
#pragma unroll
      for (int i = 0; i < NK; ++i) {
        float v = B[(size_t)(k0 + bk + i) * N + col0 + bc];
        unsigned short h = f2bf(v);
        Bh[bc * 40 + bk + i] = h;
        Bl[bc * 40 + bk + i] = f2bf(v - bf2f(h));
      }
    }
    __syncthreads();
    bf16x8 a_h = *(const bf16x8*)&Ah[(wave * 16 + l15) * 40 + l4 * 8];
    bf16x8 a_l = *(const bf16x8*)&Al[(wave * 16 + l15) * 40 + l4 * 8];
#pragma unroll
    for (int t = 0; t < NT; ++t) {
      bf16x8 b_h = *(const bf16x8*)&Bh[(t * 16 + l15) * 40 + l4 * 8];
      bf16x8 b_l = *(const bf16x8*)&Bl[(t * 16 + l15) * 40 + l4 * 8];
      acc[t] = __builtin_amdgcn_mfma_f32_16x16x32_bf16(a_h, b_h, acc[t], 0, 0, 0);
      acc[t] = __builtin_amdgcn_mfma_f32_16x16x32_bf16(a_h, b_l, acc[t], 0, 0, 0);
      acc[t] = __builtin_amdgcn_mfma_f32_16x16x32_bf16(a_l, b_h, acc[t], 0, 0, 0);
    }
    __syncthreads();
  }
#pragma unroll
  for (int t = 0; t < NT; ++t) {
#pragma unroll
    for (int r = 0; r < 4; ++r) {
      int grow = row0 + wave * 16 + l4 * 4 + r;
      if (grow < M) C[(size_t)grow * N + col0 + t * 16 + l15] = acc[t][r];
    }
  }
}

// ---------- fused aux head via MFMA ----------
template <int C>
__global__ __launch_bounds__(256) void aux_mfma(const float* __restrict__ xt,
                                                const float* __restrict__ Wh1,
                                                const float* __restrict__ bh1,
                                                const float* __restrict__ Wh2,
                                                const float* __restrict__ bh2,
                                                float* __restrict__ hout,
                                                float scale) {
  constexpr int KS = C / 32;
  constexpr int LDB = C + 8;
  __shared__ unsigned short BhS[64 * LDB], BlS[64 * LDB];
  __shared__ float w2s[64 * 32];
  __shared__ float hid[64 * 68];
  int tid = threadIdx.x;
  for (int i = tid; i < C * 64; i += 256) {
    int k = i >> 6, col = i & 63;
    float v = Wh1[i];
    unsigned short h = f2bf(v);
    BhS[col * LDB + k] = h;
    BlS[col * LDB + k] = f2bf(v - bf2f(h));
  }
  for (int i = tid; i < 64 * 32; i += 256) w2s[i] = Wh2[i];
  __syncthreads();

  int w = tid >> 6, lane = tid & 63, l15 = lane & 15, l4 = lane >> 4;
  int gr = blockIdx.x * 64 + w * 16 + l15;
  const int M2 = 2 * NN;

  f32x4 acc[4];
#pragma unroll
  for (int t = 0; t < 4; ++t) acc[t] = (f32x4){0.f, 0.f, 0.f, 0.f};

#pragma unroll
  for (int ks = 0; ks < KS; ++ks) {
    bf16x8 ah, al;
    if (gr < M2) {
      const float* p = xt + (size_t)gr * C + ks * 32 + l4 * 8;
      float4 p0 = *(const float4*)p;
      float4 p1 = *(const float4*)(p + 4);
      float v[8] = {p0.x, p0.y, p0.z, p0.w, p1.x, p1.y, p1.z, p1.w};
#pragma unroll
      for (int i = 0; i < 8; ++i) {
        unsigned short h = f2bf(v[i]);
        ah[i] = (short)h;
        al[i] = (short)f2bf(v[i] - bf2f(h));
      }
    } else {
      ah = (bf16x8){0, 0, 0, 0, 0, 0, 0, 0};
      al = ah;
    }
#pragma unroll
    for (int t = 0; t < 4; ++t) {
      bf16x8 b_h = *(const bf16x8*)&BhS[(t * 16 + l15) * LDB + ks * 32 + l4 * 8];
      bf16x8 b_l = *(const bf16x8*)&BlS[(t * 16 + l15) * LDB + ks * 32 + l4 * 8];
      acc[t] = __builtin_amdgcn_mfma_f32_16x16x32_bf16(ah, b_h, acc[t], 0, 0, 0);
      acc[t] = __builtin_amdgcn_mfma_f32_16x16x32_bf16(ah, b_l, acc[t], 0, 0, 0);
      acc[t] = __builtin_amdgcn_mfma_f32_16x16x32_bf16(al, b_h, acc[t], 0, 0, 0);
    }
  }
#pragma unroll
  for (int t = 0; t < 4; ++t) {
    float bb = bh1[t * 16 + l15];
#pragma unroll
    for (int r = 0; r < 4; ++r)
      hid[(w * 16 + l4 * 4 + r) * 68 + t * 16 + l15] = eluf(acc[t][r] + bb);
  }
  __syncthreads();
  float4 o0 = make_float4(0.f, 0.f, 0.f, 0.f), o1 = o0;
  const float* hrow = &hid[(w * 16 + l15) * 68];
#pragma unroll 8
  for (int k = 0; k < 64; ++k) {
    float hv = hrow[k];
    float4 wa = *(const float4*)&w2s[k * 32 + l4 * 8];
    float4 wb = *(const float4*)&w2s[k * 32 + l4 * 8 + 4];
    o0.x += hv * wa.x; o0.y += hv * wa.y; o0.z += hv * wa.z; o0.w += hv * wa.w;
    o1.x += hv * wb.x; o1.y += hv * wb.y; o1.z += hv * wb.z; o1.w += hv * wb.w;
  }
  if (gr < M2) {
    float4 ba = *(const float4*)&bh2[l4 * 8];
    float4 bb = *(const float4*)&bh2[l4 * 8 + 4];
    o0.x = (o0.x + ba.x) * scale; o0.y = (o0.y + ba.y) * scale;
    o0.z = (o0.z + ba.z) * scale; o0.w = (o0.w + ba.w) * scale;
    o1.x = (o1.x + bb.x) * scale; o1.y = (o1.y + bb.y) * scale;
    o1.z = (o1.z + bb.z) * scale; o1.w = (o1.w + bb.w) * scale;
    float* dst = hout + (size_t)(gr >> 1) * 64 + (gr & 1) * 32 + l4 * 8;
    *(float4*)dst = o0;
    *(float4*)(dst + 4) = o1;
  }
}

// ---------- CSR build ----------
__global__ __launch_bounds__(256) void hist_kernel(const int* __restrict__ ei,
                                                   int* __restrict__ cnt) {
  int e = blockIdx.x * 256 + threadIdx.x;
  if (e >= EPN) return;
  int d = (e < EE) ? ei[EE + e] : e - EE;
  atomicAdd(&cnt[d], 1);
}

__global__ __launch_bounds__(1024) void scan_blocks(const int* __restrict__ cnt,
                                                    int* __restrict__ tmp,
                                                    int* __restrict__ bsum) {
  __shared__ int lds[1024];
  int t = threadIdx.x, idx = blockIdx.x * 1024 + t;
  int v = (idx < NN) ? cnt[idx] : 0;
  lds[t] = v;
  __syncthreads();
  for (int off = 1; off < 1024; off <<= 1) {
    int add = (t >= off) ? lds[t - off] : 0;
    __syncthreads();
    lds[t] += add;
    __syncthreads();
  }
  if (idx < NN) tmp[idx] = lds[t];
  if (t == 1023) bsum[blockIdx.x] = lds[t];
}

__global__ __launch_bounds__(64) void scan_bsum(int* __restrict__ bsum, int nb) {
  int t = threadIdx.x;
  int v = (t < nb) ? bsum[t] : 0;
#pragma unroll
  for (int off = 1; off < 64; off <<= 1) {
    int u = __shfl_up(v, off);
    if (t >= off) v += u;
  }
  if (t < nb) bsum[t] = v;
}

__global__ __launch_bounds__(256) void scan_final(const int* __restrict__ cnt,
                                                  const int* __restrict__ tmp,
                                                  const int* __restrict__ bsum,
                                                  int* __restrict__ rowptr,
                                                  int* __restrict__ fill) {
  int idx = blockIdx.x * 256 + threadIdx.x;
  if (idx >= NN) return;
  int b = idx >> 10;
  int off = (b > 0) ? bsum[b - 1] : 0;
  int inc = tmp[idx] + off;
  rowptr[idx + 1] = inc;
  fill[idx] = inc - cnt[idx];
  if (idx == 0) rowptr[0] = 0;
}

__global__ __launch_bounds__(256) void scatter_kernel(const int* __restrict__ ei,
                                                      int* __restrict__ fill,
                                                      int* __restrict__ eids,
                                                      int* __restrict__ srcs) {
  int e = blockIdx.x * 256 + threadIdx.x;
  if (e >= EPN) return;
  int d, s;
  if (e < EE) { d = ei[EE + e]; s = ei[e]; } else { d = s = e - EE; }
  int pos = atomicAdd(&fill[d], 1);
  eids[pos] = e;
  srcs[pos] = s;
}

// ---------- layer-1 GAT: online, chunk-8, defer-max, fused LN+ELU ----------
__global__ __launch_bounds__(256) void gat256_fused(const float* __restrict__ xt,
                                                    const int* __restrict__ srcs,
                                                    const int* __restrict__ rowptr,
                                                    float* __restrict__ outb,
                                                    const float* __restrict__ g,
                                                    const float* __restrict__ b) {
  int node = (int)((blockIdx.x * (size_t)blockDim.x + threadIdx.x) >> 6);
  int lane = threadIdx.x & 63;
  if (node >= NN) return;
  int start = rowptr[node], end = rowptr[node + 1];
  float4 dstv = ((const float4*)(xt + (size_t)node * 256))[lane];
  float m = -3e38f, s = 0.f;
  float4 acc = make_float4(0.f, 0.f, 0.f, 0.f);
  int i = start;
  for (; i + 8 <= end; i += 8) {
    int sj[8];
    float4 a[8];
    float p[8];
#pragma unroll
    for (int j = 0; j < 8; ++j) sj[j] = srcs[i + j];
#pragma unroll
    for (int j = 0; j < 8; ++j) a[j] = ((const float4*)(xt + (size_t)sj[j] * 256))[lane];
#pragma unroll
    for (int j = 0; j < 8; ++j) {
      float p_ = dot4(a[j], dstv);
      p_ += __shfl_xor(p_, 1); p_ += __shfl_xor(p_, 2); p_ += __shfl_xor(p_, 4);
      p_ += __shfl_xor(p_, 8); p_ += __shfl_xor(p_, 16);
      p[j] = p_ * 0.08838834764831843f;
    }
    float pm = p[0];
#pragma unroll
    for (int j = 1; j < 8; ++j) pm = fmaxf(pm, p[j]);
    if (__any(pm > m + 8.f)) {
#pragma unroll
      for (int j = 0; j < 8; ++j) {
        float mn = fmaxf(m, p[j]);
        float scf = __expf(m - mn), w = __expf(p[j] - mn);
        s = s * scf + w;
        acc.x = acc.x * scf + w * a[j].x;
        acc.y = acc.y * scf + w * a[j].y;
        acc.z = acc.z * scf + w * a[j].z;
        acc.w = acc.w * scf + w * a[j].w;
        m = mn;
      }
    } else {
#pragma unroll
      for (int j = 0; j < 8; ++j) {
        float w = __expf(p[j] - m);
        s += w;
        acc.x = fmaf(w, a[j].x, acc.x);
        acc.y = fmaf(w, a[j].y, acc.y);
        acc.z = fmaf(w, a[j].z, acc.z);
        acc.w = fmaf(w, a[j].w, acc.w);
      }
    }
  }
  for (; i < end; ++i) {
    int s0 = srcs[i];
    float4 a0 = ((const float4*)(xt + (size_t)s0 * 256))[lane];
    float p_ = dot4(a0, dstv);
    p_ += __shfl_xor(p_, 1); p_ += __shfl_xor(p_, 2); p_ += __shfl_xor(p_, 4);
    p_ += __shfl_xor(p_, 8); p_ += __shfl_xor(p_, 16);
    p_ *= 0.08838834764831843f;
    float mn = fmaxf(m, p_);
    float scf = __expf(m - mn), w = __expf(p_ - mn);
    s = s * scf + w;
    acc.x = acc.x * scf + w * a0.x;
    acc.y = acc.y * scf + w * a0.y;
    acc.z = acc.z * scf + w * a0.z;
    acc.w = acc.w * scf + w * a0.w;
    m = mn;
  }
  float inv = 1.f / (s + 1e-16f);
  float4 v;
  v.x = acc.x * inv; v.y = acc.y * inv; v.z = acc.z * inv; v.w = acc.w * inv;
  // fused LayerNorm + ELU over 256 dims
  float sum = v.x + v.y + v.z + v.w;
#pragma unroll
  for (int o = 1; o < 64; o <<= 1) sum += __shfl_xor(sum, o);
  float mean = sum * (1.f / 256.f);
  float dx = v.x - mean, dy = v.y - mean, dz = v.z - mean, dw = v.w - mean;
  float q = dx * dx + dy * dy + dz * dz + dw * dw;
#pragma unroll
  for (int o = 1; o < 64; o <<= 1) q += __shfl_xor(q, o);
  float rstd = rsqrtf(q * (1.f / 256.f) + 1e-5f);
  float4 gg = ((const float4*)g)[lane], bb = ((const float4*)b)[lane];
  float4 r;
  r.x = eluf(dx * rstd * gg.x + bb.x);
  r.y = eluf(dy * rstd * gg.y + bb.y);
  r.z = eluf(dz * rstd * gg.z + bb.z);
  r.w = eluf(dw * rstd * gg.w + bb.w);
  ((float4*)(outb + (size_t)node * 256))[lane] = r;
}

// ---------- transposed-batch GAT, D=64 (H=2, C=32), fused epilogue ----------
// lane l: edge slot l&31, head l>>5 for logits; dim l for aggregation.
// MODE 0: layer-2 (LN+ELU over 64 -> outb[n*64+lane])
// MODE 1: layer-3 (raw logits + m,s; mean-head + LN over 32 -> outb[n*32+c])
template <int MODE>
__global__ __launch_bounds__(256) void gat64_t(const float* __restrict__ xt,
                                               const int* __restrict__ srcs,
                                               const int* __restrict__ eids,
                                               const int* __restrict__ rowptr,
                                               float* __restrict__ outb,
                                               float* __restrict__ logit_out,
                                               float* __restrict__ mbuf,
                                               float* __restrict__ sbuf,
                                               const float* __restrict__ g,
                                               const float* __restrict__ b) {
  int node = (int)((blockIdx.x * (size_t)blockDim.x + threadIdx.x) >> 6);
  int lane = threadIdx.x & 63;
  if (node >= NN) return;
  int l32 = lane & 31, half = lane >> 5;
  int start = rowptr[node], end = rowptr[node + 1];
  const float4* drow = (const float4*)(xt + (size_t)node * 64 + half * 32);
  float4 d0 = drow[0], d1 = drow[1], d2 = drow[2], d3 = drow[3];
  float4 d4 = drow[4], d5 = drow[5], d6 = drow[6], d7 = drow[7];
  float m = -3e38f, s = 0.f, acc = 0.f;

  for (int base = start; base < end; base += 32) {
    int cnt = end - base;
    cnt = cnt > 32 ? 32 : cnt;
    int sidx = srcs[base + (l32 < cnt ? l32 : 0)];
    const float4* srow = (const float4*)(xt + (size_t)sidx * 64 + half * 32);
    float4 s0 = srow[0], s1 = srow[1], s2 = srow[2], s3 = srow[3];
    float4 s4 = srow[4], s5 = srow[5], s6 = srow[6], s7 = srow[7];
    float p = dot4(s0, d0) + dot4(s1, d1) + dot4(s2, d2) + dot4(s3, d3) +
              dot4(s4, d4) + dot4(s5, d5) + dot4(s6, d6) + dot4(s7, d7);
    p *= 0.17677669529663687f;  // 1/sqrt(32)
    if (MODE == 1) {
      if (l32 < cnt) logit_out[(size_t)eids[base + l32] * 2 + half] = p;
    }
    if (l32 >= cnt) p = -3e38f;
    // batch max within half
    float bm = p;
    bm = fmaxf(bm, __shfl_xor(bm, 1));
    bm = fmaxf(bm, __shfl_xor(bm, 2));
    bm = fmaxf(bm, __shfl_xor(bm, 4));
    bm = fmaxf(bm, __shfl_xor(bm, 8));
    bm = fmaxf(bm, __shfl_xor(bm, 16));
    float mn = fmaxf(m, bm);
    float scf = __expf(m - mn);
    float w = (l32 < cnt) ? __expf(p - mn) : 0.f;
    float bs = w;
    bs += __shfl_xor(bs, 1);
    bs += __shfl_xor(bs, 2);
    bs += __shfl_xor(bs, 4);
    bs += __shfl_xor(bs, 8);
    bs += __shfl_xor(bs, 16);
    s = s * scf + bs;
    acc *= scf;
    m = mn;
    // phase 2: coalesced weighted aggregation
#pragma unroll 4
    for (int e = 0; e < cnt; ++e) {
      int sj = __shfl(sidx, e);
      float wv = __shfl(w, e + (half << 5));
      float a = xt[(size_t)sj * 64 + lane];
      acc = fmaf(wv, a, acc);
    }
  }
  float inv = 1.f / (s + 1e-16f);
  float v = acc * inv;
  if (MODE == 0) {
    float sum = v;
#pragma unroll
    for (int o = 1; o < 64; o <<= 1) sum += __shfl_xor(sum, o);
    float mean = sum * (1.f / 64.f);
    float dv = v - mean;
    float q = dv * dv;
#pragma unroll
    for (int o = 1; o < 64; o <<= 1) q += __shfl_xor(q, o);
    float rstd = rsqrtf(q * (1.f / 64.f) + 1e-5f);
    outb[(size_t)node * 64 + lane] = eluf(dv * rstd * g[lane] + b[lane]);
  } else {
    if (l32 == 0) {
      mbuf[(size_t)node * 2 + half] = m;
      sbuf[(size_t)node * 2 + half] = s;
    }
    float t = __shfl_xor(v, 32);
    float y = 0.5f * (v + t);
    float sum = y;
#pragma unroll
    for (int o = 1; o < 32; o <<= 1) sum += __shfl_xor(sum, o);
    float mean = sum * (1.f / 32.f);
    float dy = y - mean;
    float q = dy * dy;
#pragma unroll
    for (int o = 1; o < 32; o <<= 1) q += __shfl_xor(q, o);
    float rstd = rsqrtf(q * (1.f / 32.f) + 1e-5f);
    if (half == 0) outb[(size_t)node * 32 + l32] = dy * rstd * g[l32] + b[l32];
  }
}

// ---------- alpha fix-up ----------
__global__ __launch_bounds__(256) void alpha_fix(float* __restrict__ al,
                                                 const int* __restrict__ ei,
                                                 const float* __restrict__ mbuf,
                                                 const float* __restrict__ sbuf) {
  size_t i = blockIdx.x * (size_t)blockDim.x + threadIdx.x;
  if (i >= (size_t)EPN * 2) return;
  int e = (int)(i >> 1), h = (int)(i & 1);
  int d = (e < EE) ? ei[EE + e] : e - EE;
  al[i] = expf(al[i] - mbuf[(size_t)d * 2 + h]) / (sbuf[(size_t)d * 2 + h] + 1e-16f);
}

extern "C" void kernel_launch(void* const* d_in, const int* in_sizes, int n_in,
                              void* d_out, int out_size, void* d_ws, size_t ws_size,
                              hipStream_t stream) {
  const float* x    = (const float*)d_in[0];
  const int*   ei   = (const int*)d_in[1];
  const float* W1   = (const float*)d_in[2];
  const float* Wh1a = (const float*)d_in[3];
  const float* bh1a = (const float*)d_in[4];
  const float* Wh2a = (const float*)d_in[5];
  const float* bh2a = (const float*)d_in[6];
  const float* g1   = (const float*)d_in[7];
  const float* b1   = (const float*)d_in[8];
  const float* W2   = (const float*)d_in[9];
  const float* Wh1b = (const float*)d_in[10];
  const float* bh1b = (const float*)d_in[11];
  const float* Wh2b = (const float*)d_in[12];
  const float* bh2b = (const float*)d_in[13];
  const float* g2   = (const float*)d_in[14];
  const float* b2   = (const float*)d_in[15];
  const float* W3   = (const float*)d_in[16];
  const float* Wh1c = (const float*)d_in[17];
  const float* bh1c = (const float*)d_in[18];
  const float* Wh2c = (const float*)d_in[19];
  const float* bh2c = (const float*)d_in[20];
  const float* g3   = (const float*)d_in[21];
  const float* b3   = (const float*)d_in[22];

  float* out  = (float*)d_out;
  float* o_x3 = out;                           // N*32
  float* o_h1 = out + (size_t)NN * 32;         // N*64
  float* o_h2 = o_h1 + (size_t)NN * 64;        // N*64
  float* o_h3 = o_h2 + (size_t)NN * 64;        // N*64
  float* o_al = o_h3 + (size_t)NN * 64;        // EPN*2 (logits then alpha)

  float* ws  = (float*)d_ws;
  float* A   = ws;                             // N*256
  float* Bb  = ws + (size_t)NN * 256;          // N*256
  int* cnt    = (int*)(Bb + (size_t)NN * 256); // NN
  int* rowptr = cnt + NN;                      // NN+1
  int* fill   = rowptr + NN + 1;               // NN
  int* eids   = fill + NN;                     // EPN
  int* srcs   = eids + EPN;                    // EPN
  int* tmp    = srcs + EPN;                    // NN
  int* bsum   = tmp + NN;                      // 64
  float* mbuf = (float*)(bsum + 64);           // NN*2
  float* sbuf = mbuf + (size_t)NN * 2;         // NN*2
  ushort_t* W1h = (ushort_t*)(sbuf + (size_t)NN * 2);  // 256*512
  ushort_t* W1l = W1h + 256 * 512;                     // 256*512

  dim3 blk(256);
  int gEdges = (EPN + 255) / 256;
  int gNodeW = (NN * 64 + 255) / 256;
  int gRows = (NN + 63) / 64;
  int gPairs = (int)(((size_t)EPN * 2 + 255) / 256);
  int gAux = (2 * NN + 63) / 64;
  int nbScan = (NN + 1023) / 1024;

  // ---------------- CSR by dst + W1 preconversion ----------------
  conv_w1<<<512, blk, 0, stream>>>(W1, W1h, W1l);
  hipMemsetAsync(cnt, 0, (size_t)NN * 4, stream);
  hist_kernel<<<gEdges, blk, 0, stream>>>(ei, cnt);
  scan_blocks<<<nbScan, 1024, 0, stream>>>(cnt, tmp, bsum);
  scan_bsum<<<1, 64, 0, stream>>>(bsum, nbScan);
  scan_final<<<(NN + 255) / 256, blk, 0, stream>>>(cnt, tmp, bsum, rowptr, fill);
  scatter_kernel<<<gEdges, blk, 0, stream>>>(ei, fill, eids, srcs);

  // ---------------- Layer 1: 512 -> 2x128 (concat) ----------------
  gemm1_mfma<<<gRows, blk, 0, stream>>>(x, W1h, W1l, A, NN);
  aux_mfma<128><<<gAux, blk, 0, stream>>>(A, Wh1a, bh1a, Wh2a, bh2a, o_h1, 1.0f);
  gat256_fused<<<gNodeW, blk, 0, stream>>>(A, srcs, rowptr, Bb, g1, b1);

  // ---------------- Layer 2: 256 -> 2x32 (concat) ----------------
  gemm_mfma<4><<<dim3(1, gRows), blk, 0, stream>>>(Bb, W2, A, NN, 64, 256);
  aux_mfma<32><<<gAux, blk, 0, stream>>>(A, Wh1b, bh1b, Wh2b, bh2b, o_h2, 0.5f);
  gat64_t<0><<<gNodeW, blk, 0, stream>>>(A, srcs, nullptr, rowptr, Bb, nullptr,
                                         nullptr, nullptr, g2, b2);

  // ---------------- Layer 3: 64 -> 2x32 (mean) ----------------
  gemm_mfma<4><<<dim3(1, gRows), blk, 0, stream>>>(Bb, W3, A, NN, 64, 64);
  aux_mfma<32><<<gAux, blk, 0, stream>>>(A, Wh1c, bh1c, Wh2c, bh2c, o_h3, 1.0f);
  gat64_t<1><<<gNodeW, blk, 0, stream>>>(A, srcs, eids, rowptr, o_x3, o_al,
                                         mbuf, sbuf, g3, b3);
  alpha_fix<<<gPairs, blk, 0, stream>>>(o_al, ei, mbuf, sbuf);
}